// Round 7
// baseline (236.984 us; speedup 1.0000x reference)
//
#include <hip/hip_runtime.h>
#include <hip/hip_bf16.h>
#include <stdint.h>

#define SEQ 2048
#define NB 4
#define NH 12
#define DMODEL 768
#define DK 64
#define NTOK (NB*SEQ)          // 8192
#define QSCALE 0.18033688011f  // 0.125 * log2(e)

typedef __bf16 bf16_t;
typedef __attribute__((ext_vector_type(4))) bf16_t bf16x4;
typedef __attribute__((ext_vector_type(8))) bf16_t bf16x8;
typedef __attribute__((ext_vector_type(4))) float f32x4;

typedef __attribute__((address_space(3))) uint32_t lds_u32_t;
typedef const __attribute__((address_space(1))) uint32_t glb_u32_t;

__device__ inline void load_lds16(const void* g, void* l) {
    __builtin_amdgcn_global_load_lds((glb_u32_t*)g, (lds_u32_t*)l, 16, 0, 0);
}

// ---------------- fp32 -> bf16 convert ----------------
__global__ void cvt_f32_bf16(const float* __restrict__ src, bf16_t* __restrict__ dst, int n4) {
    int i = blockIdx.x * blockDim.x + threadIdx.x;
    if (i < n4) {
        float4 v = ((const float4*)src)[i];
        bf16x4 o;
        o[0] = (bf16_t)v.x; o[1] = (bf16_t)v.y; o[2] = (bf16_t)v.z; o[3] = (bf16_t)v.w;
        ((bf16x4*)dst)[i] = o;
    }
}

// =================== GEMM: 128x128 tile, BK=32, dbuf distinct LDS arrays ===================
// barrier -> STAGE(next half, other buf) -> compute(cur). Distinct __shared__ arrays =>
// no DMA/ds_read alias => no vmcnt(0) drain mid-loop. (256,3): 170-VGPR cap, ~100 live, no spill.

#define GSTAGE(AS, BS, KB) do { \
    _Pragma("unroll") \
    for (int j = 0; j < 2; j++) { \
        int c = tid + j*256; \
        int row = c >> 2, cb = (c & 3) * 8; \
        load_lds16(Ap_ + (size_t)(mt*128 + row)*DMODEL + (KB) + cb, AS + c*8); \
        load_lds16(Bp_ + (size_t)(nt*128 + row)*DMODEL + (KB) + cb, BS + c*8); \
    } \
} while (0)

#define GCOMPUTE(AS, BS) do { \
    bf16x8 af[4], bfr[4]; \
    _Pragma("unroll") \
    for (int f = 0; f < 4; f++) { \
        af[f]  = *(const bf16x8*)(AS + (wy*64 + f*16 + lr)*32 + lq*8); \
        bfr[f] = *(const bf16x8*)(BS + (wx*64 + f*16 + lr)*32 + lq*8); \
    } \
    _Pragma("unroll") \
    for (int fm = 0; fm < 4; fm++) \
        _Pragma("unroll") \
        for (int fn = 0; fn < 4; fn++) \
            acc[fm][fn] = __builtin_amdgcn_mfma_f32_16x16x32_bf16(af[fm], bfr[fn], acc[fm][fn], 0, 0, 0); \
} while (0)

#define GEMM_BODY() \
    f32x4 acc[4][4] = {}; \
    GSTAGE(As0, Bs0, 0); \
    for (int kb = 0; kb < DMODEL; kb += 64) { \
        __syncthreads(); \
        GSTAGE(As1, Bs1, kb + 32); \
        GCOMPUTE(As0, Bs0); \
        __syncthreads(); \
        if (kb + 64 < DMODEL) GSTAGE(As0, Bs0, kb + 64); \
        GCOMPUTE(As1, Bs1); \
    }

// ---------------- QKV projection GEMM ----------------
__global__ __launch_bounds__(256, 3) void gemm_qkv(
    const bf16_t* __restrict__ Ap_, const bf16_t* __restrict__ Bp_,
    bf16_t* __restrict__ Qo, bf16_t* __restrict__ Ko, bf16_t* __restrict__ VTo)
{
    __shared__ bf16_t As0[128*32];
    __shared__ bf16_t Bs0[128*32];
    __shared__ bf16_t As1[128*32];
    __shared__ bf16_t Bs1[128*32];
    const int mt = blockIdx.x, nt = blockIdx.y;
    const int tid = threadIdx.x;
    const int w = tid >> 6, lane = tid & 63;
    const int wx = w & 1, wy = w >> 1;
    const int lr = lane & 15, lq = lane >> 4;

    GEMM_BODY();

    const int t = nt / 6;                       // 0=Q,1=K,2=V
    const int ob = (nt % 6) * 128 + wx * 64;
    #pragma unroll
    for (int fm = 0; fm < 4; fm++)
        #pragma unroll
        for (int fn = 0; fn < 4; fn++)
            #pragma unroll
            for (int r = 0; r < 4; r++) {
                int m = mt*128 + wy*64 + fm*16 + lq*4 + r;
                int o = ob + fn*16 + lr;
                int b = m >> 11, s = m & 2047;
                int h = o >> 6, dk = o & 63;
                float v = acc[fm][fn][r];
                if (t == 0)      Qo[(size_t)((b*NH + h)*SEQ + s)*DK + dk] = (bf16_t)(v * QSCALE);
                else if (t == 1) Ko[(size_t)((b*NH + h)*SEQ + s)*DK + dk] = (bf16_t)v;
                else             VTo[(size_t)((b*NH + h)*DK + dk)*SEQ + s] = (bf16_t)v;
            }
}

// ---------------- O projection GEMM (fp32 out) ----------------
__global__ __launch_bounds__(256, 3) void gemm_oproj(
    const bf16_t* __restrict__ Ap_, const bf16_t* __restrict__ Bp_, float* __restrict__ out)
{
    __shared__ bf16_t As0[128*32];
    __shared__ bf16_t Bs0[128*32];
    __shared__ bf16_t As1[128*32];
    __shared__ bf16_t Bs1[128*32];
    const int mt = blockIdx.x, nt = blockIdx.y;
    const int tid = threadIdx.x;
    const int w = tid >> 6, lane = tid & 63;
    const int wx = w & 1, wy = w >> 1;
    const int lr = lane & 15, lq = lane >> 4;

    GEMM_BODY();

    #pragma unroll
    for (int fm = 0; fm < 4; fm++)
        #pragma unroll
        for (int fn = 0; fn < 4; fn++)
            #pragma unroll
            for (int r = 0; r < 4; r++) {
                int m = mt*128 + wy*64 + fm*16 + lq*4 + r;
                int n = nt*128 + wx*64 + fn*16 + lr;
                out[(size_t)m*DMODEL + n] = acc[fm][fn][r];
            }
}

// ---------------- Flash attention (causal) ----------------
// Single 16-row q-strip per wave; block = 64-row q-tile; grid (32,48)=1536 blocks, heavy
// tiles first (qt = 31-bx) for queue balance. K/V staged via global_load_lds into distinct
// dbuf arrays (no alias -> no vmcnt drain), XOR-swizzled; one barrier per 64-k window.
// P fragment-major LDS round-trip. Q pre-scaled by 0.125*log2e; fixed m=0 softmax; l via
// ones-MFMA. LDS 40960 B x 4 blocks = 160 KiB exactly; (256,4): ~107 live VGPR < 128 cap
// (bv loaded after exp phase to keep the peak down).

#define ASTAGE(KS, VS, KB) do { \
    _Pragma("unroll") \
    for (int j = 0; j < 2; j++) { \
        int rr = w*16 + j*8 + srow; \
        load_lds16(Kp + (size_t)((KB) + rr)*DK + g*8,  &KS[w*1024 + j*512 + lane*8]); \
        load_lds16(Vp + (size_t)rr*SEQ + (KB) + g*8,   &VS[w*1024 + j*512 + lane*8]); \
    } \
} while (0)

#define AITER(KSC, VSC, KSN, VSN, T) do { \
    __syncthreads(); \
    if ((T) + 1 < nIter) ASTAGE(KSN, VSN, ((T)+1)*64); \
    const int sw = lr & 7; \
    const bool masked = ((T) == nIter - 1); \
    f32x4 sc[4]; \
    _Pragma("unroll") \
    for (int ct = 0; ct < 4; ct++) { \
        int row = ct*16 + lr; \
        bf16x8 bk0 = *(const bf16x8*)(&KSC[row*64 + ((lq    ) ^ sw)*8]); \
        bf16x8 bk1 = *(const bf16x8*)(&KSC[row*64 + ((lq + 4) ^ sw)*8]); \
        f32x4 s = {}; \
        s = __builtin_amdgcn_mfma_f32_16x16x32_bf16(aq0, bk0, s, 0, 0, 0); \
        s = __builtin_amdgcn_mfma_f32_16x16x32_bf16(aq1, bk1, s, 0, 0, 0); \
        sc[ct] = s; \
    } \
    _Pragma("unroll") \
    for (int ct = 0; ct < 4; ct++) \
        _Pragma("unroll") \
        for (int r = 0; r < 4; r++) { \
            float p = __builtin_amdgcn_exp2f(sc[ct][r]); \
            if (masked) { \
                int kl = ct*16 + lr, ql = w*16 + lq*4 + r; \
                p = (kl <= ql) ? p : 0.0f; \
            } \
            Pw[(ct>>1)*512 + (lq*4 + r + 16*((ct*2 + (lr>>3)) & 3))*8 + ((lr&7)>>1)*2 + (lr&1)] = (bf16_t)p; \
        } \
    { \
        bf16x8 ap0 = *(const bf16x8*)(Pw + lane*8); \
        bf16x8 ap1 = *(const bf16x8*)(Pw + 512 + lane*8); \
        _Pragma("unroll") \
        for (int c = 0; c < 4; c++) { \
            int row = c*16 + lr; \
            bf16x8 bv0 = *(const bf16x8*)(&VSC[row*64 + ((lq    ) ^ sw)*8]); \
            bf16x8 bv1 = *(const bf16x8*)(&VSC[row*64 + ((lq + 4) ^ sw)*8]); \
            acc[c] = __builtin_amdgcn_mfma_f32_16x16x32_bf16(ap0, bv0, acc[c], 0, 0, 0); \
            acc[c] = __builtin_amdgcn_mfma_f32_16x16x32_bf16(ap1, bv1, acc[c], 0, 0, 0); \
        } \
        al = __builtin_amdgcn_mfma_f32_16x16x32_bf16(ap0, ones, al, 0, 0, 0); \
        al = __builtin_amdgcn_mfma_f32_16x16x32_bf16(ap1, ones, al, 0, 0, 0); \
    } \
} while (0)

__global__ __launch_bounds__(256, 4) void attn(
    const bf16_t* __restrict__ Q, const bf16_t* __restrict__ K,
    const bf16_t* __restrict__ VT, bf16_t* __restrict__ O)
{
    __shared__ bf16_t Ks0[64*64];
    __shared__ bf16_t Vs0[64*64];
    __shared__ bf16_t Ks1[64*64];
    __shared__ bf16_t Vs1[64*64];
    __shared__ bf16_t P[4][1024];

    const int qt = 31 - blockIdx.x;          // heavy tiles first
    const int bh = blockIdx.y;
    const int w = threadIdx.x >> 6, lane = threadIdx.x & 63;
    const int lr = lane & 15, lq = lane >> 4;
    const int qs = qt*64 + w*16;
    const int srow = lane >> 3;              // 0..7
    const int g    = (lane & 7) ^ srow;      // XOR-swizzled chunk to fetch

    const bf16_t* Qp = Q  + (size_t)bh*SEQ*DK;
    const bf16_t* Kp = K  + (size_t)bh*SEQ*DK;
    const bf16_t* Vp = VT + (size_t)bh*DK*SEQ;
    bf16_t* Pw = &P[w][0];

    const bf16x8 aq0 = *(const bf16x8*)(Qp + (size_t)(qs+lr)*DK + lq*8);
    const bf16x8 aq1 = *(const bf16x8*)(Qp + (size_t)(qs+lr)*DK + 32 + lq*8);

    bf16x8 ones;
    #pragma unroll
    for (int i = 0; i < 8; i++) ones[i] = (bf16_t)1.0f;

    f32x4 acc[4] = {};
    f32x4 al = {};

    const int nIter = qt + 1;                // windows of 64 k

    ASTAGE(Ks0, Vs0, 0);
    int t = 0;
    while (true) {
        AITER(Ks0, Vs0, Ks1, Vs1, t); t++;
        if (t >= nIter) break;
        AITER(Ks1, Vs1, Ks0, Vs0, t); t++;
        if (t >= nIter) break;
    }

    const int b = bh / NH, h = bh % NH;
    #pragma unroll
    for (int r = 0; r < 4; r++) {
        float rl = 1.0f / al[r];
        int q = qs + lq*4 + r;
        bf16_t* op = O + (size_t)(b*SEQ + q)*DMODEL + h*DK;
        #pragma unroll
        for (int c = 0; c < 4; c++) op[c*16 + lr] = (bf16_t)(acc[c][r] * rl);
    }
}

extern "C" void kernel_launch(void* const* d_in, const int* in_sizes, int n_in,
                              void* d_out, int out_size, void* d_ws, size_t ws_size,
                              hipStream_t stream) {
    const float* x    = (const float*)d_in[0];
    const float* wqkv = (const float*)d_in[1];
    const float* wo   = (const float*)d_in[2];
    float* out = (float*)d_out;

    char* ws = (char*)d_ws;
    const size_t SZ_X   = (size_t)NTOK*DMODEL*2;
    const size_t SZ_WQ  = (size_t)3*DMODEL*DMODEL*2;
    const size_t SZ_WO  = (size_t)DMODEL*DMODEL*2;
    const size_t SZ_HD  = (size_t)NB*NH*SEQ*DK*2;
    bf16_t* xb    = (bf16_t*)(ws);
    bf16_t* wqkvb = (bf16_t*)(ws + SZ_X);
    bf16_t* wob   = (bf16_t*)(ws + SZ_X + SZ_WQ);
    bf16_t* Qb    = (bf16_t*)(ws + SZ_X + SZ_WQ + SZ_WO);
    bf16_t* Kb    = (bf16_t*)(ws + SZ_X + SZ_WQ + SZ_WO + SZ_HD);
    bf16_t* VTb   = (bf16_t*)(ws + SZ_X + SZ_WQ + SZ_WO + 2*SZ_HD);
    bf16_t* Ob    = (bf16_t*)(ws + SZ_X + SZ_WQ + SZ_WO + 3*SZ_HD);

    int n_x  = NTOK*DMODEL/4;
    int n_wq = 3*DMODEL*DMODEL/4;
    int n_wo = DMODEL*DMODEL/4;
    cvt_f32_bf16<<<(n_x  + 255)/256, 256, 0, stream>>>(x,    xb,    n_x);
    cvt_f32_bf16<<<(n_wq + 255)/256, 256, 0, stream>>>(wqkv, wqkvb, n_wq);
    cvt_f32_bf16<<<(n_wo + 255)/256, 256, 0, stream>>>(wo,   wob,   n_wo);

    gemm_qkv<<<dim3(NTOK/128, 3*DMODEL/128), 256, 0, stream>>>(xb, wqkvb, Qb, Kb, VTb);
    attn<<<dim3(32, NB*NH), 256, 0, stream>>>(Qb, Kb, VTb, Ob);
    gemm_oproj<<<dim3(NTOK/128, DMODEL/128), 256, 0, stream>>>(Ob, wob, out);
}

// Round 8
// 203.591 us; speedup vs baseline: 1.1640x; 1.1640x over previous
//
#include <hip/hip_runtime.h>
#include <hip/hip_bf16.h>
#include <stdint.h>

#define SEQ 2048
#define NB 4
#define NH 12
#define DMODEL 768
#define DK 64
#define NTOK (NB*SEQ)          // 8192
#define QSCALE 0.18033688011f  // 0.125 * log2(e)

#define N_X4   (NTOK*DMODEL/4)          // 1572864
#define N_WQ4  (3*DMODEL*DMODEL/4)      // 442368
#define N_WO4  (DMODEL*DMODEL/4)        // 147456

typedef __bf16 bf16_t;
typedef __attribute__((ext_vector_type(4))) bf16_t bf16x4;
typedef __attribute__((ext_vector_type(8))) bf16_t bf16x8;
typedef __attribute__((ext_vector_type(4))) float f32x4;

typedef __attribute__((address_space(3))) uint32_t lds_u32_t;
typedef const __attribute__((address_space(1))) uint32_t glb_u32_t;

__device__ inline void load_lds16(const void* g, void* l) {
    __builtin_amdgcn_global_load_lds((glb_u32_t*)g, (lds_u32_t*)l, 16, 0, 0);
}

// ---------------- fp32 -> bf16 convert (x, wqkv, wo fused; dst regions contiguous) ----------------
__global__ void cvt_all(const float* __restrict__ x, const float* __restrict__ wq,
                        const float* __restrict__ wo, bf16_t* __restrict__ dst) {
    int i = blockIdx.x * blockDim.x + threadIdx.x;   // grid sized exactly
    const float* src; int off;
    if (i < N_X4)              { src = x;  off = i; }
    else if (i < N_X4 + N_WQ4) { src = wq; off = i - N_X4; }
    else                       { src = wo; off = i - (N_X4 + N_WQ4); }
    float4 v = ((const float4*)src)[off];
    bf16x4 o;
    o[0] = (bf16_t)v.x; o[1] = (bf16_t)v.y; o[2] = (bf16_t)v.z; o[3] = (bf16_t)v.w;
    ((bf16x4*)dst)[i] = o;
}

// =================== GEMM: 128x128 tile, BK=32, dbuf distinct LDS arrays (R7-proven) ===================
#define GSTAGE(AS, BS, KB) do { \
    _Pragma("unroll") \
    for (int j = 0; j < 2; j++) { \
        int c = tid + j*256; \
        int row = c >> 2, cb = (c & 3) * 8; \
        load_lds16(Ap_ + (size_t)(mt*128 + row)*DMODEL + (KB) + cb, AS + c*8); \
        load_lds16(Bp_ + (size_t)(nt*128 + row)*DMODEL + (KB) + cb, BS + c*8); \
    } \
} while (0)

#define GCOMPUTE(AS, BS) do { \
    bf16x8 af[4], bfr[4]; \
    _Pragma("unroll") \
    for (int f = 0; f < 4; f++) { \
        af[f]  = *(const bf16x8*)(AS + (wy*64 + f*16 + lr)*32 + lq*8); \
        bfr[f] = *(const bf16x8*)(BS + (wx*64 + f*16 + lr)*32 + lq*8); \
    } \
    _Pragma("unroll") \
    for (int fm = 0; fm < 4; fm++) \
        _Pragma("unroll") \
        for (int fn = 0; fn < 4; fn++) \
            acc[fm][fn] = __builtin_amdgcn_mfma_f32_16x16x32_bf16(af[fm], bfr[fn], acc[fm][fn], 0, 0, 0); \
} while (0)

#define GEMM_BODY() \
    f32x4 acc[4][4] = {}; \
    GSTAGE(As0, Bs0, 0); \
    for (int kb = 0; kb < DMODEL; kb += 64) { \
        __syncthreads(); \
        GSTAGE(As1, Bs1, kb + 32); \
        GCOMPUTE(As0, Bs0); \
        __syncthreads(); \
        if (kb + 64 < DMODEL) GSTAGE(As0, Bs0, kb + 64); \
        GCOMPUTE(As1, Bs1); \
    }

// ---------------- QKV projection GEMM ----------------
__global__ __launch_bounds__(256, 3) void gemm_qkv(
    const bf16_t* __restrict__ Ap_, const bf16_t* __restrict__ Bp_,
    bf16_t* __restrict__ Qo, bf16_t* __restrict__ Ko, bf16_t* __restrict__ VTo)
{
    __shared__ bf16_t As0[128*32];
    __shared__ bf16_t Bs0[128*32];
    __shared__ bf16_t As1[128*32];
    __shared__ bf16_t Bs1[128*32];
    const int mt = blockIdx.x, nt = blockIdx.y;
    const int tid = threadIdx.x;
    const int w = tid >> 6, lane = tid & 63;
    const int wx = w & 1, wy = w >> 1;
    const int lr = lane & 15, lq = lane >> 4;

    GEMM_BODY();

    const int t = nt / 6;                       // 0=Q,1=K,2=V
    const int ob = (nt % 6) * 128 + wx * 64;
    #pragma unroll
    for (int fm = 0; fm < 4; fm++)
        #pragma unroll
        for (int fn = 0; fn < 4; fn++)
            #pragma unroll
            for (int r = 0; r < 4; r++) {
                int m = mt*128 + wy*64 + fm*16 + lq*4 + r;
                int o = ob + fn*16 + lr;
                int b = m >> 11, s = m & 2047;
                int h = o >> 6, dk = o & 63;
                float v = acc[fm][fn][r];
                if (t == 0)      Qo[(size_t)((b*NH + h)*SEQ + s)*DK + dk] = (bf16_t)(v * QSCALE);
                else if (t == 1) Ko[(size_t)((b*NH + h)*SEQ + s)*DK + dk] = (bf16_t)v;
                else             VTo[(size_t)((b*NH + h)*DK + dk)*SEQ + s] = (bf16_t)v;
            }
}

// ---------------- O projection GEMM (fp32 out) ----------------
__global__ __launch_bounds__(256, 3) void gemm_oproj(
    const bf16_t* __restrict__ Ap_, const bf16_t* __restrict__ Bp_, float* __restrict__ out)
{
    __shared__ bf16_t As0[128*32];
    __shared__ bf16_t Bs0[128*32];
    __shared__ bf16_t As1[128*32];
    __shared__ bf16_t Bs1[128*32];
    const int mt = blockIdx.x, nt = blockIdx.y;
    const int tid = threadIdx.x;
    const int w = tid >> 6, lane = tid & 63;
    const int wx = w & 1, wy = w >> 1;
    const int lr = lane & 15, lq = lane >> 4;

    GEMM_BODY();

    #pragma unroll
    for (int fm = 0; fm < 4; fm++)
        #pragma unroll
        for (int fn = 0; fn < 4; fn++)
            #pragma unroll
            for (int r = 0; r < 4; r++) {
                int m = mt*128 + wy*64 + fm*16 + lq*4 + r;
                int n = nt*128 + wx*64 + fn*16 + lr;
                out[(size_t)m*DMODEL + n] = acc[fm][fn][r];
            }
}

// ---------------- Flash attention (causal) — R6-proven paired version ----------------
// Block = paired q-tiles {qtA, 31-qtA} (uniform 33 strip-tiles). grid (16,48)=768 blocks
// = exactly 3/CU at (256,3). K/V staged via global_load_lds into DISTINCT dbuf arrays
// (no alias -> no vmcnt drain), XOR-swizzled; one barrier per 64-k window; DMA(t+1)
// lands during compute(t). Paired strips: one bk/bv LDS read feeds two score/PV chains
// (2x DS amortization + intra-wave ILP in the overlap region; 26% fewer total windows
// than single-strip). P fragment-major round-trip. Q pre-scaled by 0.125*log2e; fixed
// m=0 softmax; l via ones-MFMA. (256,3): 170-VGPR cap >= ~150 live (no spill; R5's
// (256,4)=128 cap spilled 500 MB).

#define ASTAGE(KS, VS, KB) do { \
    _Pragma("unroll") \
    for (int j = 0; j < 2; j++) { \
        int rr = w*16 + j*8 + srow; \
        load_lds16(Kp + (size_t)((KB) + rr)*DK + g*8,  &KS[w*1024 + j*512 + lane*8]); \
        load_lds16(Vp + (size_t)rr*SEQ + (KB) + g*8,   &VS[w*1024 + j*512 + lane*8]); \
    } \
} while (0)

#define STRIP(A0, A1, ACC, AL, MASKED) do { \
    f32x4 sc[4]; \
    _Pragma("unroll") \
    for (int ct = 0; ct < 4; ct++) { \
        f32x4 s = {}; \
        s = __builtin_amdgcn_mfma_f32_16x16x32_bf16(A0, bk[ct][0], s, 0, 0, 0); \
        s = __builtin_amdgcn_mfma_f32_16x16x32_bf16(A1, bk[ct][1], s, 0, 0, 0); \
        sc[ct] = s; \
    } \
    _Pragma("unroll") \
    for (int ct = 0; ct < 4; ct++) \
        _Pragma("unroll") \
        for (int r = 0; r < 4; r++) { \
            float p = __builtin_amdgcn_exp2f(sc[ct][r]); \
            if (MASKED) { \
                int kl = ct*16 + lr, ql = w*16 + lq*4 + r; \
                p = (kl <= ql) ? p : 0.0f; \
            } \
            Pw[(ct>>1)*512 + (lq*4 + r + 16*((ct*2 + (lr>>3)) & 3))*8 + ((lr&7)>>1)*2 + (lr&1)] = (bf16_t)p; \
        } \
    { \
        bf16x8 ap0 = *(const bf16x8*)(Pw + lane*8); \
        bf16x8 ap1 = *(const bf16x8*)(Pw + 512 + lane*8); \
        _Pragma("unroll") \
        for (int c = 0; c < 4; c++) { \
            ACC[c] = __builtin_amdgcn_mfma_f32_16x16x32_bf16(ap0, bv[c][0], ACC[c], 0, 0, 0); \
            ACC[c] = __builtin_amdgcn_mfma_f32_16x16x32_bf16(ap1, bv[c][1], ACC[c], 0, 0, 0); \
        } \
        AL = __builtin_amdgcn_mfma_f32_16x16x32_bf16(ap0, ones, AL, 0, 0, 0); \
        AL = __builtin_amdgcn_mfma_f32_16x16x32_bf16(ap1, ones, AL, 0, 0, 0); \
    } \
} while (0)

#define AITER(KSC, VSC, KSN, VSN, T) do { \
    __syncthreads(); \
    if ((T) + 1 < nIter) ASTAGE(KSN, VSN, ((T)+1)*64); \
    bf16x8 bk[4][2], bv[4][2]; \
    const int sw = lr & 7; \
    _Pragma("unroll") \
    for (int ct = 0; ct < 4; ct++) { \
        int row = ct*16 + lr; \
        bk[ct][0] = *(const bf16x8*)(&KSC[row*64 + ((lq    ) ^ sw)*8]); \
        bk[ct][1] = *(const bf16x8*)(&KSC[row*64 + ((lq + 4) ^ sw)*8]); \
        bv[ct][0] = *(const bf16x8*)(&VSC[row*64 + ((lq    ) ^ sw)*8]); \
        bv[ct][1] = *(const bf16x8*)(&VSC[row*64 + ((lq + 4) ^ sw)*8]); \
    } \
    if ((T) <= qtA) { \
        if ((T) == qtA) { STRIP(aqA0, aqA1, accA, alA, true); } \
        else            { STRIP(aqA0, aqA1, accA, alA, false); } \
    } \
    if ((T) == nIter - 1) { STRIP(aqB0, aqB1, accB, alB, true); } \
    else                  { STRIP(aqB0, aqB1, accB, alB, false); } \
} while (0)

__global__ __launch_bounds__(256, 3) void attn(
    const bf16_t* __restrict__ Q, const bf16_t* __restrict__ K,
    const bf16_t* __restrict__ VT, bf16_t* __restrict__ O)
{
    __shared__ bf16_t Ks0[64*64];
    __shared__ bf16_t Vs0[64*64];
    __shared__ bf16_t Ks1[64*64];
    __shared__ bf16_t Vs1[64*64];
    __shared__ bf16_t P[4][1024];

    const int qtA = blockIdx.x;          // 0..15
    const int qtB = 31 - qtA;            // 16..31
    const int bh  = blockIdx.y;
    const int w = threadIdx.x >> 6, lane = threadIdx.x & 63;
    const int lr = lane & 15, lq = lane >> 4;
    const int qsA = qtA*64 + w*16;
    const int qsB = qtB*64 + w*16;
    const int srow = lane >> 3;              // 0..7
    const int g    = (lane & 7) ^ srow;      // XOR-swizzled chunk to fetch

    const bf16_t* Qp = Q  + (size_t)bh*SEQ*DK;
    const bf16_t* Kp = K  + (size_t)bh*SEQ*DK;
    const bf16_t* Vp = VT + (size_t)bh*DK*SEQ;
    bf16_t* Pw = &P[w][0];

    const bf16x8 aqA0 = *(const bf16x8*)(Qp + (size_t)(qsA+lr)*DK + lq*8);
    const bf16x8 aqA1 = *(const bf16x8*)(Qp + (size_t)(qsA+lr)*DK + 32 + lq*8);
    const bf16x8 aqB0 = *(const bf16x8*)(Qp + (size_t)(qsB+lr)*DK + lq*8);
    const bf16x8 aqB1 = *(const bf16x8*)(Qp + (size_t)(qsB+lr)*DK + 32 + lq*8);

    bf16x8 ones;
    #pragma unroll
    for (int i = 0; i < 8; i++) ones[i] = (bf16_t)1.0f;

    f32x4 accA[4] = {}, accB[4] = {};
    f32x4 alA = {}, alB = {};

    const int nIter = 32 - qtA;          // 17..32, block-uniform

    ASTAGE(Ks0, Vs0, 0);
    int t = 0;
    while (true) {
        AITER(Ks0, Vs0, Ks1, Vs1, t); t++;
        if (t >= nIter) break;
        AITER(Ks1, Vs1, Ks0, Vs0, t); t++;
        if (t >= nIter) break;
    }

    const int b = bh / NH, h = bh % NH;
    #pragma unroll
    for (int r = 0; r < 4; r++) {
        float rlA = 1.0f / alA[r];
        float rlB = 1.0f / alB[r];
        int qa = qsA + lq*4 + r;
        int qb = qsB + lq*4 + r;
        bf16_t* opA = O + (size_t)(b*SEQ + qa)*DMODEL + h*DK;
        bf16_t* opB = O + (size_t)(b*SEQ + qb)*DMODEL + h*DK;
        #pragma unroll
        for (int c = 0; c < 4; c++) {
            opA[c*16 + lr] = (bf16_t)(accA[c][r] * rlA);
            opB[c*16 + lr] = (bf16_t)(accB[c][r] * rlB);
        }
    }
}

extern "C" void kernel_launch(void* const* d_in, const int* in_sizes, int n_in,
                              void* d_out, int out_size, void* d_ws, size_t ws_size,
                              hipStream_t stream) {
    const float* x    = (const float*)d_in[0];
    const float* wqkv = (const float*)d_in[1];
    const float* wo   = (const float*)d_in[2];
    float* out = (float*)d_out;

    char* ws = (char*)d_ws;
    const size_t SZ_X   = (size_t)NTOK*DMODEL*2;
    const size_t SZ_WQ  = (size_t)3*DMODEL*DMODEL*2;
    const size_t SZ_WO  = (size_t)DMODEL*DMODEL*2;
    const size_t SZ_HD  = (size_t)NB*NH*SEQ*DK*2;
    bf16_t* xb    = (bf16_t*)(ws);
    bf16_t* wqkvb = (bf16_t*)(ws + SZ_X);
    bf16_t* wob   = (bf16_t*)(ws + SZ_X + SZ_WQ);
    bf16_t* Qb    = (bf16_t*)(ws + SZ_X + SZ_WQ + SZ_WO);
    bf16_t* Kb    = (bf16_t*)(ws + SZ_X + SZ_WQ + SZ_WO + SZ_HD);
    bf16_t* VTb   = (bf16_t*)(ws + SZ_X + SZ_WQ + SZ_WO + 2*SZ_HD);
    bf16_t* Ob    = (bf16_t*)(ws + SZ_X + SZ_WQ + SZ_WO + 3*SZ_HD);

    // xb/wqkvb/wob are contiguous: one fused convert kernel (grid exact multiple of 256)
    cvt_all<<<(N_X4 + N_WQ4 + N_WO4) / 256, 256, 0, stream>>>(x, wqkv, wo, xb);

    gemm_qkv<<<dim3(NTOK/128, 3*DMODEL/128), 256, 0, stream>>>(xb, wqkvb, Qb, Kb, VTb);
    attn<<<dim3(16, NB*NH), 256, 0, stream>>>(Qb, Kb, VTb, Ob);
    gemm_oproj<<<dim3(NTOK/128, DMODEL/128), 256, 0, stream>>>(Ob, wob, out);
}

// Round 9
// 202.300 us; speedup vs baseline: 1.1714x; 1.0064x over previous
//
#include <hip/hip_runtime.h>
#include <hip/hip_bf16.h>
#include <stdint.h>

#define SEQ 2048
#define NB 4
#define NH 12
#define DMODEL 768
#define DK 64
#define NTOK (NB*SEQ)          // 8192
#define QSCALE 0.18033688011f  // 0.125 * log2(e)

#define N_X4   (NTOK*DMODEL/4)          // 1572864
#define N_WQ4  (3*DMODEL*DMODEL/4)      // 442368
#define N_WO4  (DMODEL*DMODEL/4)        // 147456

typedef __bf16 bf16_t;
typedef __attribute__((ext_vector_type(4))) bf16_t bf16x4;
typedef __attribute__((ext_vector_type(8))) bf16_t bf16x8;
typedef __attribute__((ext_vector_type(4))) float f32x4;

typedef __attribute__((address_space(3))) uint32_t lds_u32_t;
typedef const __attribute__((address_space(1))) uint32_t glb_u32_t;

__device__ inline void load_lds16(const void* g, void* l) {
    __builtin_amdgcn_global_load_lds((glb_u32_t*)g, (lds_u32_t*)l, 16, 0, 0);
}

// ---------------- fp32 -> bf16 convert (x, wqkv, wo fused; dst regions contiguous) ----------------
__global__ void cvt_all(const float* __restrict__ x, const float* __restrict__ wq,
                        const float* __restrict__ wo, bf16_t* __restrict__ dst) {
    int i = blockIdx.x * blockDim.x + threadIdx.x;   // grid sized exactly
    const float* src; int off;
    if (i < N_X4)              { src = x;  off = i; }
    else if (i < N_X4 + N_WQ4) { src = wq; off = i - N_X4; }
    else                       { src = wo; off = i - (N_X4 + N_WQ4); }
    float4 v = ((const float4*)src)[off];
    bf16x4 o;
    o[0] = (bf16_t)v.x; o[1] = (bf16_t)v.y; o[2] = (bf16_t)v.z; o[3] = (bf16_t)v.w;
    ((bf16x4*)dst)[i] = o;
}

// =================== QKV GEMM: 128x128 tile, BK=32, dbuf distinct LDS arrays ===================
#define GSTAGE(AS, BS, KB) do { \
    _Pragma("unroll") \
    for (int j = 0; j < 2; j++) { \
        int c = tid + j*256; \
        int row = c >> 2, cb = (c & 3) * 8; \
        load_lds16(Ap_ + (size_t)(mt*128 + row)*DMODEL + (KB) + cb, AS + c*8); \
        load_lds16(Bp_ + (size_t)(nt*128 + row)*DMODEL + (KB) + cb, BS + c*8); \
    } \
} while (0)

#define GCOMPUTE(AS, BS) do { \
    bf16x8 af[4], bfr[4]; \
    _Pragma("unroll") \
    for (int f = 0; f < 4; f++) { \
        af[f]  = *(const bf16x8*)(AS + (wy*64 + f*16 + lr)*32 + lq*8); \
        bfr[f] = *(const bf16x8*)(BS + (wx*64 + f*16 + lr)*32 + lq*8); \
    } \
    _Pragma("unroll") \
    for (int fm = 0; fm < 4; fm++) \
        _Pragma("unroll") \
        for (int fn = 0; fn < 4; fn++) \
            acc[fm][fn] = __builtin_amdgcn_mfma_f32_16x16x32_bf16(af[fm], bfr[fn], acc[fm][fn], 0, 0, 0); \
} while (0)

// ---------------- QKV projection GEMM: (256,4) — 1152 blocks -> one clean round of 4/CU ----------------
__global__ __launch_bounds__(256, 4) void gemm_qkv(
    const bf16_t* __restrict__ Ap_, const bf16_t* __restrict__ Bp_,
    bf16_t* __restrict__ Qo, bf16_t* __restrict__ Ko, bf16_t* __restrict__ VTo)
{
    __shared__ bf16_t As0[128*32];
    __shared__ bf16_t Bs0[128*32];
    __shared__ bf16_t As1[128*32];
    __shared__ bf16_t Bs1[128*32];
    const int mt = blockIdx.x, nt = blockIdx.y;
    const int tid = threadIdx.x;
    const int w = tid >> 6, lane = tid & 63;
    const int wx = w & 1, wy = w >> 1;
    const int lr = lane & 15, lq = lane >> 4;

    f32x4 acc[4][4] = {};
    GSTAGE(As0, Bs0, 0);
    for (int kb = 0; kb < DMODEL; kb += 64) {
        __syncthreads();
        GSTAGE(As1, Bs1, kb + 32);
        GCOMPUTE(As0, Bs0);
        __syncthreads();
        if (kb + 64 < DMODEL) GSTAGE(As0, Bs0, kb + 64);
        GCOMPUTE(As1, Bs1);
    }

    const int t = nt / 6;                       // 0=Q,1=K,2=V
    const int ob = (nt % 6) * 128 + wx * 64;
    #pragma unroll
    for (int fm = 0; fm < 4; fm++)
        #pragma unroll
        for (int fn = 0; fn < 4; fn++)
            #pragma unroll
            for (int r = 0; r < 4; r++) {
                int m = mt*128 + wy*64 + fm*16 + lq*4 + r;
                int o = ob + fn*16 + lr;
                int b = m >> 11, s = m & 2047;
                int h = o >> 6, dk = o & 63;
                float v = acc[fm][fn][r];
                if (t == 0)      Qo[(size_t)((b*NH + h)*SEQ + s)*DK + dk] = (bf16_t)(v * QSCALE);
                else if (t == 1) Ko[(size_t)((b*NH + h)*SEQ + s)*DK + dk] = (bf16_t)v;
                else             VTo[(size_t)((b*NH + h)*DK + dk)*SEQ + s] = (bf16_t)v;
            }
}

// ---------------- O projection GEMM: 128x64 tile, grid (64,12)=768 = exactly 3/CU ----------------
// Wave w: wy=w>>1 (m 64-half), wx=w&1 (n 32-half); acc 4x2. Staging 768 chunks/half: 3/thread.
#define OSTAGE(AS, BS, KB) do { \
    _Pragma("unroll") \
    for (int j = 0; j < 3; j++) { \
        int c = tid + j*256; \
        if (c < 512) { \
            int row = c >> 2, cb = (c & 3) * 8; \
            load_lds16(Ap_ + (size_t)(mt*128 + row)*DMODEL + (KB) + cb, AS + c*8); \
        } else { \
            int c2 = c - 512; \
            int row = c2 >> 2, cb = (c2 & 3) * 8; \
            load_lds16(Bp_ + (size_t)(nt*64 + row)*DMODEL + (KB) + cb, BS + c2*8); \
        } \
    } \
} while (0)

#define OCOMPUTE(AS, BS) do { \
    bf16x8 af[4], bfr[2]; \
    _Pragma("unroll") \
    for (int f = 0; f < 4; f++) \
        af[f]  = *(const bf16x8*)(AS + (wy*64 + f*16 + lr)*32 + lq*8); \
    _Pragma("unroll") \
    for (int f = 0; f < 2; f++) \
        bfr[f] = *(const bf16x8*)(BS + (wx*32 + f*16 + lr)*32 + lq*8); \
    _Pragma("unroll") \
    for (int fm = 0; fm < 4; fm++) \
        _Pragma("unroll") \
        for (int fn = 0; fn < 2; fn++) \
            acc[fm][fn] = __builtin_amdgcn_mfma_f32_16x16x32_bf16(af[fm], bfr[fn], acc[fm][fn], 0, 0, 0); \
} while (0)

__global__ __launch_bounds__(256, 4) void gemm_oproj(
    const bf16_t* __restrict__ Ap_, const bf16_t* __restrict__ Bp_, float* __restrict__ out)
{
    __shared__ bf16_t As0[128*32];
    __shared__ bf16_t Bs0[64*32];
    __shared__ bf16_t As1[128*32];
    __shared__ bf16_t Bs1[64*32];
    const int mt = blockIdx.x, nt = blockIdx.y;
    const int tid = threadIdx.x;
    const int w = tid >> 6, lane = tid & 63;
    const int wx = w & 1, wy = w >> 1;
    const int lr = lane & 15, lq = lane >> 4;

    f32x4 acc[4][2] = {};
    OSTAGE(As0, Bs0, 0);
    for (int kb = 0; kb < DMODEL; kb += 64) {
        __syncthreads();
        OSTAGE(As1, Bs1, kb + 32);
        OCOMPUTE(As0, Bs0);
        __syncthreads();
        if (kb + 64 < DMODEL) OSTAGE(As0, Bs0, kb + 64);
        OCOMPUTE(As1, Bs1);
    }

    #pragma unroll
    for (int fm = 0; fm < 4; fm++)
        #pragma unroll
        for (int fn = 0; fn < 2; fn++)
            #pragma unroll
            for (int r = 0; r < 4; r++) {
                int m = mt*128 + wy*64 + fm*16 + lq*4 + r;
                int n = nt*64 + wx*32 + fn*16 + lr;
                out[(size_t)m*DMODEL + n] = acc[fm][fn][r];
            }
}

// ---------------- Flash attention (causal) — R6-proven paired version (unchanged) ----------------
#define ASTAGE(KS, VS, KB) do { \
    _Pragma("unroll") \
    for (int j = 0; j < 2; j++) { \
        int rr = w*16 + j*8 + srow; \
        load_lds16(Kp + (size_t)((KB) + rr)*DK + g*8,  &KS[w*1024 + j*512 + lane*8]); \
        load_lds16(Vp + (size_t)rr*SEQ + (KB) + g*8,   &VS[w*1024 + j*512 + lane*8]); \
    } \
} while (0)

#define STRIP(A0, A1, ACC, AL, MASKED) do { \
    f32x4 sc[4]; \
    _Pragma("unroll") \
    for (int ct = 0; ct < 4; ct++) { \
        f32x4 s = {}; \
        s = __builtin_amdgcn_mfma_f32_16x16x32_bf16(A0, bk[ct][0], s, 0, 0, 0); \
        s = __builtin_amdgcn_mfma_f32_16x16x32_bf16(A1, bk[ct][1], s, 0, 0, 0); \
        sc[ct] = s; \
    } \
    _Pragma("unroll") \
    for (int ct = 0; ct < 4; ct++) \
        _Pragma("unroll") \
        for (int r = 0; r < 4; r++) { \
            float p = __builtin_amdgcn_exp2f(sc[ct][r]); \
            if (MASKED) { \
                int kl = ct*16 + lr, ql = w*16 + lq*4 + r; \
                p = (kl <= ql) ? p : 0.0f; \
            } \
            Pw[(ct>>1)*512 + (lq*4 + r + 16*((ct*2 + (lr>>3)) & 3))*8 + ((lr&7)>>1)*2 + (lr&1)] = (bf16_t)p; \
        } \
    { \
        bf16x8 ap0 = *(const bf16x8*)(Pw + lane*8); \
        bf16x8 ap1 = *(const bf16x8*)(Pw + 512 + lane*8); \
        _Pragma("unroll") \
        for (int c = 0; c < 4; c++) { \
            ACC[c] = __builtin_amdgcn_mfma_f32_16x16x32_bf16(ap0, bv[c][0], ACC[c], 0, 0, 0); \
            ACC[c] = __builtin_amdgcn_mfma_f32_16x16x32_bf16(ap1, bv[c][1], ACC[c], 0, 0, 0); \
        } \
        AL = __builtin_amdgcn_mfma_f32_16x16x32_bf16(ap0, ones, AL, 0, 0, 0); \
        AL = __builtin_amdgcn_mfma_f32_16x16x32_bf16(ap1, ones, AL, 0, 0, 0); \
    } \
} while (0)

#define AITER(KSC, VSC, KSN, VSN, T) do { \
    __syncthreads(); \
    if ((T) + 1 < nIter) ASTAGE(KSN, VSN, ((T)+1)*64); \
    bf16x8 bk[4][2], bv[4][2]; \
    const int sw = lr & 7; \
    _Pragma("unroll") \
    for (int ct = 0; ct < 4; ct++) { \
        int row = ct*16 + lr; \
        bk[ct][0] = *(const bf16x8*)(&KSC[row*64 + ((lq    ) ^ sw)*8]); \
        bk[ct][1] = *(const bf16x8*)(&KSC[row*64 + ((lq + 4) ^ sw)*8]); \
        bv[ct][0] = *(const bf16x8*)(&VSC[row*64 + ((lq    ) ^ sw)*8]); \
        bv[ct][1] = *(const bf16x8*)(&VSC[row*64 + ((lq + 4) ^ sw)*8]); \
    } \
    if ((T) <= qtA) { \
        if ((T) == qtA) { STRIP(aqA0, aqA1, accA, alA, true); } \
        else            { STRIP(aqA0, aqA1, accA, alA, false); } \
    } \
    if ((T) == nIter - 1) { STRIP(aqB0, aqB1, accB, alB, true); } \
    else                  { STRIP(aqB0, aqB1, accB, alB, false); } \
} while (0)

__global__ __launch_bounds__(256, 3) void attn(
    const bf16_t* __restrict__ Q, const bf16_t* __restrict__ K,
    const bf16_t* __restrict__ VT, bf16_t* __restrict__ O)
{
    __shared__ bf16_t Ks0[64*64];
    __shared__ bf16_t Vs0[64*64];
    __shared__ bf16_t Ks1[64*64];
    __shared__ bf16_t Vs1[64*64];
    __shared__ bf16_t P[4][1024];

    const int qtA = blockIdx.x;          // 0..15
    const int qtB = 31 - qtA;            // 16..31
    const int bh  = blockIdx.y;
    const int w = threadIdx.x >> 6, lane = threadIdx.x & 63;
    const int lr = lane & 15, lq = lane >> 4;
    const int qsA = qtA*64 + w*16;
    const int qsB = qtB*64 + w*16;
    const int srow = lane >> 3;              // 0..7
    const int g    = (lane & 7) ^ srow;      // XOR-swizzled chunk to fetch

    const bf16_t* Qp = Q  + (size_t)bh*SEQ*DK;
    const bf16_t* Kp = K  + (size_t)bh*SEQ*DK;
    const bf16_t* Vp = VT + (size_t)bh*DK*SEQ;
    bf16_t* Pw = &P[w][0];

    const bf16x8 aqA0 = *(const bf16x8*)(Qp + (size_t)(qsA+lr)*DK + lq*8);
    const bf16x8 aqA1 = *(const bf16x8*)(Qp + (size_t)(qsA+lr)*DK + 32 + lq*8);
    const bf16x8 aqB0 = *(const bf16x8*)(Qp + (size_t)(qsB+lr)*DK + lq*8);
    const bf16x8 aqB1 = *(const bf16x8*)(Qp + (size_t)(qsB+lr)*DK + 32 + lq*8);

    bf16x8 ones;
    #pragma unroll
    for (int i = 0; i < 8; i++) ones[i] = (bf16_t)1.0f;

    f32x4 accA[4] = {}, accB[4] = {};
    f32x4 alA = {}, alB = {};

    const int nIter = 32 - qtA;          // 17..32, block-uniform

    ASTAGE(Ks0, Vs0, 0);
    int t = 0;
    while (true) {
        AITER(Ks0, Vs0, Ks1, Vs1, t); t++;
        if (t >= nIter) break;
        AITER(Ks1, Vs1, Ks0, Vs0, t); t++;
        if (t >= nIter) break;
    }

    const int b = bh / NH, h = bh % NH;
    #pragma unroll
    for (int r = 0; r < 4; r++) {
        float rlA = 1.0f / alA[r];
        float rlB = 1.0f / alB[r];
        int qa = qsA + lq*4 + r;
        int qb = qsB + lq*4 + r;
        bf16_t* opA = O + (size_t)(b*SEQ + qa)*DMODEL + h*DK;
        bf16_t* opB = O + (size_t)(b*SEQ + qb)*DMODEL + h*DK;
        #pragma unroll
        for (int c = 0; c < 4; c++) {
            opA[c*16 + lr] = (bf16_t)(accA[c][r] * rlA);
            opB[c*16 + lr] = (bf16_t)(accB[c][r] * rlB);
        }
    }
}

extern "C" void kernel_launch(void* const* d_in, const int* in_sizes, int n_in,
                              void* d_out, int out_size, void* d_ws, size_t ws_size,
                              hipStream_t stream) {
    const float* x    = (const float*)d_in[0];
    const float* wqkv = (const float*)d_in[1];
    const float* wo   = (const float*)d_in[2];
    float* out = (float*)d_out;

    char* ws = (char*)d_ws;
    const size_t SZ_X   = (size_t)NTOK*DMODEL*2;
    const size_t SZ_WQ  = (size_t)3*DMODEL*DMODEL*2;
    const size_t SZ_WO  = (size_t)DMODEL*DMODEL*2;
    const size_t SZ_HD  = (size_t)NB*NH*SEQ*DK*2;
    bf16_t* xb    = (bf16_t*)(ws);
    bf16_t* wqkvb = (bf16_t*)(ws + SZ_X);
    bf16_t* wob   = (bf16_t*)(ws + SZ_X + SZ_WQ);
    bf16_t* Qb    = (bf16_t*)(ws + SZ_X + SZ_WQ + SZ_WO);
    bf16_t* Kb    = (bf16_t*)(ws + SZ_X + SZ_WQ + SZ_WO + SZ_HD);
    bf16_t* VTb   = (bf16_t*)(ws + SZ_X + SZ_WQ + SZ_WO + 2*SZ_HD);
    bf16_t* Ob    = (bf16_t*)(ws + SZ_X + SZ_WQ + SZ_WO + 3*SZ_HD);

    cvt_all<<<(N_X4 + N_WQ4 + N_WO4) / 256, 256, 0, stream>>>(x, wqkv, wo, xb);

    gemm_qkv<<<dim3(NTOK/128, 3*DMODEL/128), 256, 0, stream>>>(xb, wqkvb, Qb, Kb, VTb);
    attn<<<dim3(16, NB*NH), 256, 0, stream>>>(Qb, Kb, VTb, Ob);
    gemm_oproj<<<dim3(NTOK/128, DMODEL/64), 256, 0, stream>>>(Ob, wob, out);
}

// Round 10
// 194.865 us; speedup vs baseline: 1.2161x; 1.0382x over previous
//
#include <hip/hip_runtime.h>
#include <hip/hip_bf16.h>
#include <stdint.h>

#define SEQ 2048
#define NB 4
#define NH 12
#define DMODEL 768
#define DK 64
#define NTOK (NB*SEQ)          // 8192
#define QSCALE 0.18033688011f  // 0.125 * log2(e)

#define N_X4   (NTOK*DMODEL/4)          // 1572864
#define N_WQ4  (3*DMODEL*DMODEL/4)      // 442368
#define N_WO4  (DMODEL*DMODEL/4)        // 147456

typedef __bf16 bf16_t;
typedef __attribute__((ext_vector_type(4))) bf16_t bf16x4;
typedef __attribute__((ext_vector_type(8))) bf16_t bf16x8;
typedef __attribute__((ext_vector_type(4))) float f32x4;

typedef __attribute__((address_space(3))) uint32_t lds_u32_t;
typedef const __attribute__((address_space(1))) uint32_t glb_u32_t;

__device__ inline void load_lds16(const void* g, void* l) {
    __builtin_amdgcn_global_load_lds((glb_u32_t*)g, (lds_u32_t*)l, 16, 0, 0);
}

// ---------------- fp32 -> bf16 convert (x, wqkv, wo fused; dst regions contiguous) ----------------
__global__ void cvt_all(const float* __restrict__ x, const float* __restrict__ wq,
                        const float* __restrict__ wo, bf16_t* __restrict__ dst) {
    int i = blockIdx.x * blockDim.x + threadIdx.x;   // grid sized exactly
    const float* src; int off;
    if (i < N_X4)              { src = x;  off = i; }
    else if (i < N_X4 + N_WQ4) { src = wq; off = i - N_X4; }
    else                       { src = wo; off = i - (N_X4 + N_WQ4); }
    float4 v = ((const float4*)src)[off];
    bf16x4 o;
    o[0] = (bf16_t)v.x; o[1] = (bf16_t)v.y; o[2] = (bf16_t)v.z; o[3] = (bf16_t)v.w;
    ((bf16x4*)dst)[i] = o;
}

// =================== QKV GEMM: 128x192 tile, BK=32, dbuf distinct LDS arrays ===================
// grid (64,12) = 768 blocks = exactly 3.0/CU (was 1152 = 4.5/CU -> half-round tail).
// Wave tile 64x96: 24 MFMA per 10 ds_read_b128 (ratio 2.4 vs 2.0 at 128x128).
// A: 512 chunks, B: 768 chunks per 32-k half-window -> 5 chunks/thread. (256,3): ~166 live regs.
#define QSTAGE(AS, BS, KB) do { \
    _Pragma("unroll") \
    for (int j = 0; j < 5; j++) { \
        int c = tid + j*256; \
        if (c < 512) { \
            int row = c >> 2, cb = (c & 3) * 8; \
            load_lds16(Ap_ + (size_t)(mt*128 + row)*DMODEL + (KB) + cb, AS + c*8); \
        } else { \
            int c2 = c - 512; \
            int row = c2 >> 2, cb = (c2 & 3) * 8; \
            load_lds16(Bp_ + (size_t)(nt*192 + row)*DMODEL + (KB) + cb, BS + c2*8); \
        } \
    } \
} while (0)

#define QCOMPUTE(AS, BS) do { \
    bf16x8 af[4]; \
    _Pragma("unroll") \
    for (int f = 0; f < 4; f++) \
        af[f] = *(const bf16x8*)(AS + (wy*64 + f*16 + lr)*32 + lq*8); \
    _Pragma("unroll") \
    for (int fn = 0; fn < 6; fn++) { \
        bf16x8 bfr = *(const bf16x8*)(BS + (wx*96 + fn*16 + lr)*32 + lq*8); \
        _Pragma("unroll") \
        for (int fm = 0; fm < 4; fm++) \
            acc[fm][fn] = __builtin_amdgcn_mfma_f32_16x16x32_bf16(af[fm], bfr, acc[fm][fn], 0, 0, 0); \
    } \
} while (0)

__global__ __launch_bounds__(256, 3) void gemm_qkv(
    const bf16_t* __restrict__ Ap_, const bf16_t* __restrict__ Bp_,
    bf16_t* __restrict__ Qo, bf16_t* __restrict__ Ko, bf16_t* __restrict__ VTo)
{
    __shared__ bf16_t As0[128*32];
    __shared__ bf16_t Bs0[192*32];
    __shared__ bf16_t As1[128*32];
    __shared__ bf16_t Bs1[192*32];
    const int mt = blockIdx.x, nt = blockIdx.y;
    const int tid = threadIdx.x;
    const int w = tid >> 6, lane = tid & 63;
    const int wx = w & 1, wy = w >> 1;
    const int lr = lane & 15, lq = lane >> 4;

    f32x4 acc[4][6] = {};
    QSTAGE(As0, Bs0, 0);
    for (int kb = 0; kb < DMODEL; kb += 64) {
        __syncthreads();
        QSTAGE(As1, Bs1, kb + 32);
        QCOMPUTE(As0, Bs0);
        __syncthreads();
        if (kb + 64 < DMODEL) QSTAGE(As0, Bs0, kb + 64);
        QCOMPUTE(As1, Bs1);
    }

    const int t = nt >> 2;                      // 768 = 4*192: tile never spans Q/K/V
    const int ob = (nt & 3) * 192 + wx * 96;    // col base within 768
    #pragma unroll
    for (int fm = 0; fm < 4; fm++)
        #pragma unroll
        for (int fn = 0; fn < 6; fn++)
            #pragma unroll
            for (int r = 0; r < 4; r++) {
                int m = mt*128 + wy*64 + fm*16 + lq*4 + r;
                int o = ob + fn*16 + lr;
                int b = m >> 11, s = m & 2047;
                int h = o >> 6, dk = o & 63;
                float v = acc[fm][fn][r];
                if (t == 0)      Qo[(size_t)((b*NH + h)*SEQ + s)*DK + dk] = (bf16_t)(v * QSCALE);
                else if (t == 1) Ko[(size_t)((b*NH + h)*SEQ + s)*DK + dk] = (bf16_t)v;
                else             VTo[(size_t)((b*NH + h)*DK + dk)*SEQ + s] = (bf16_t)v;
            }
}

// ---------------- O projection GEMM: 128x64 tile, grid (64,12)=768 = exactly 3/CU ----------------
#define OSTAGE(AS, BS, KB) do { \
    _Pragma("unroll") \
    for (int j = 0; j < 3; j++) { \
        int c = tid + j*256; \
        if (c < 512) { \
            int row = c >> 2, cb = (c & 3) * 8; \
            load_lds16(Ap_ + (size_t)(mt*128 + row)*DMODEL + (KB) + cb, AS + c*8); \
        } else { \
            int c2 = c - 512; \
            int row = c2 >> 2, cb = (c2 & 3) * 8; \
            load_lds16(Bp_ + (size_t)(nt*64 + row)*DMODEL + (KB) + cb, BS + c2*8); \
        } \
    } \
} while (0)

#define OCOMPUTE(AS, BS) do { \
    bf16x8 af[4], bfr[2]; \
    _Pragma("unroll") \
    for (int f = 0; f < 4; f++) \
        af[f]  = *(const bf16x8*)(AS + (wy*64 + f*16 + lr)*32 + lq*8); \
    _Pragma("unroll") \
    for (int f = 0; f < 2; f++) \
        bfr[f] = *(const bf16x8*)(BS + (wx*32 + f*16 + lr)*32 + lq*8); \
    _Pragma("unroll") \
    for (int fm = 0; fm < 4; fm++) \
        _Pragma("unroll") \
        for (int fn = 0; fn < 2; fn++) \
            acc[fm][fn] = __builtin_amdgcn_mfma_f32_16x16x32_bf16(af[fm], bfr[fn], acc[fm][fn], 0, 0, 0); \
} while (0)

__global__ __launch_bounds__(256, 4) void gemm_oproj(
    const bf16_t* __restrict__ Ap_, const bf16_t* __restrict__ Bp_, float* __restrict__ out)
{
    __shared__ bf16_t As0[128*32];
    __shared__ bf16_t Bs0[64*32];
    __shared__ bf16_t As1[128*32];
    __shared__ bf16_t Bs1[64*32];
    const int mt = blockIdx.x, nt = blockIdx.y;
    const int tid = threadIdx.x;
    const int w = tid >> 6, lane = tid & 63;
    const int wx = w & 1, wy = w >> 1;
    const int lr = lane & 15, lq = lane >> 4;

    f32x4 acc[4][2] = {};
    OSTAGE(As0, Bs0, 0);
    for (int kb = 0; kb < DMODEL; kb += 64) {
        __syncthreads();
        OSTAGE(As1, Bs1, kb + 32);
        OCOMPUTE(As0, Bs0);
        __syncthreads();
        if (kb + 64 < DMODEL) OSTAGE(As0, Bs0, kb + 64);
        OCOMPUTE(As1, Bs1);
    }

    #pragma unroll
    for (int fm = 0; fm < 4; fm++)
        #pragma unroll
        for (int fn = 0; fn < 2; fn++)
            #pragma unroll
            for (int r = 0; r < 4; r++) {
                int m = mt*128 + wy*64 + fm*16 + lq*4 + r;
                int n = nt*64 + wx*32 + fn*16 + lr;
                out[(size_t)m*DMODEL + n] = acc[fm][fn][r];
            }
}

// ---------------- Flash attention (causal) — R6-proven paired version (unchanged) ----------------
#define ASTAGE(KS, VS, KB) do { \
    _Pragma("unroll") \
    for (int j = 0; j < 2; j++) { \
        int rr = w*16 + j*8 + srow; \
        load_lds16(Kp + (size_t)((KB) + rr)*DK + g*8,  &KS[w*1024 + j*512 + lane*8]); \
        load_lds16(Vp + (size_t)rr*SEQ + (KB) + g*8,   &VS[w*1024 + j*512 + lane*8]); \
    } \
} while (0)

#define STRIP(A0, A1, ACC, AL, MASKED) do { \
    f32x4 sc[4]; \
    _Pragma("unroll") \
    for (int ct = 0; ct < 4; ct++) { \
        f32x4 s = {}; \
        s = __builtin_amdgcn_mfma_f32_16x16x32_bf16(A0, bk[ct][0], s, 0, 0, 0); \
        s = __builtin_amdgcn_mfma_f32_16x16x32_bf16(A1, bk[ct][1], s, 0, 0, 0); \
        sc[ct] = s; \
    } \
    _Pragma("unroll") \
    for (int ct = 0; ct < 4; ct++) \
        _Pragma("unroll") \
        for (int r = 0; r < 4; r++) { \
            float p = __builtin_amdgcn_exp2f(sc[ct][r]); \
            if (MASKED) { \
                int kl = ct*16 + lr, ql = w*16 + lq*4 + r; \
                p = (kl <= ql) ? p : 0.0f; \
            } \
            Pw[(ct>>1)*512 + (lq*4 + r + 16*((ct*2 + (lr>>3)) & 3))*8 + ((lr&7)>>1)*2 + (lr&1)] = (bf16_t)p; \
        } \
    { \
        bf16x8 ap0 = *(const bf16x8*)(Pw + lane*8); \
        bf16x8 ap1 = *(const bf16x8*)(Pw + 512 + lane*8); \
        _Pragma("unroll") \
        for (int c = 0; c < 4; c++) { \
            ACC[c] = __builtin_amdgcn_mfma_f32_16x16x32_bf16(ap0, bv[c][0], ACC[c], 0, 0, 0); \
            ACC[c] = __builtin_amdgcn_mfma_f32_16x16x32_bf16(ap1, bv[c][1], ACC[c], 0, 0, 0); \
        } \
        AL = __builtin_amdgcn_mfma_f32_16x16x32_bf16(ap0, ones, AL, 0, 0, 0); \
        AL = __builtin_amdgcn_mfma_f32_16x16x32_bf16(ap1, ones, AL, 0, 0, 0); \
    } \
} while (0)

#define AITER(KSC, VSC, KSN, VSN, T) do { \
    __syncthreads(); \
    if ((T) + 1 < nIter) ASTAGE(KSN, VSN, ((T)+1)*64); \
    bf16x8 bk[4][2], bv[4][2]; \
    const int sw = lr & 7; \
    _Pragma("unroll") \
    for (int ct = 0; ct < 4; ct++) { \
        int row = ct*16 + lr; \
        bk[ct][0] = *(const bf16x8*)(&KSC[row*64 + ((lq    ) ^ sw)*8]); \
        bk[ct][1] = *(const bf16x8*)(&KSC[row*64 + ((lq + 4) ^ sw)*8]); \
        bv[ct][0] = *(const bf16x8*)(&VSC[row*64 + ((lq    ) ^ sw)*8]); \
        bv[ct][1] = *(const bf16x8*)(&VSC[row*64 + ((lq + 4) ^ sw)*8]); \
    } \
    if ((T) <= qtA) { \
        if ((T) == qtA) { STRIP(aqA0, aqA1, accA, alA, true); } \
        else            { STRIP(aqA0, aqA1, accA, alA, false); } \
    } \
    if ((T) == nIter - 1) { STRIP(aqB0, aqB1, accB, alB, true); } \
    else                  { STRIP(aqB0, aqB1, accB, alB, false); } \
} while (0)

__global__ __launch_bounds__(256, 3) void attn(
    const bf16_t* __restrict__ Q, const bf16_t* __restrict__ K,
    const bf16_t* __restrict__ VT, bf16_t* __restrict__ O)
{
    __shared__ bf16_t Ks0[64*64];
    __shared__ bf16_t Vs0[64*64];
    __shared__ bf16_t Ks1[64*64];
    __shared__ bf16_t Vs1[64*64];
    __shared__ bf16_t P[4][1024];

    const int qtA = blockIdx.x;          // 0..15
    const int qtB = 31 - qtA;            // 16..31
    const int bh  = blockIdx.y;
    const int w = threadIdx.x >> 6, lane = threadIdx.x & 63;
    const int lr = lane & 15, lq = lane >> 4;
    const int qsA = qtA*64 + w*16;
    const int qsB = qtB*64 + w*16;
    const int srow = lane >> 3;              // 0..7
    const int g    = (lane & 7) ^ srow;      // XOR-swizzled chunk to fetch

    const bf16_t* Qp = Q  + (size_t)bh*SEQ*DK;
    const bf16_t* Kp = K  + (size_t)bh*SEQ*DK;
    const bf16_t* Vp = VT + (size_t)bh*DK*SEQ;
    bf16_t* Pw = &P[w][0];

    const bf16x8 aqA0 = *(const bf16x8*)(Qp + (size_t)(qsA+lr)*DK + lq*8);
    const bf16x8 aqA1 = *(const bf16x8*)(Qp + (size_t)(qsA+lr)*DK + 32 + lq*8);
    const bf16x8 aqB0 = *(const bf16x8*)(Qp + (size_t)(qsB+lr)*DK + lq*8);
    const bf16x8 aqB1 = *(const bf16x8*)(Qp + (size_t)(qsB+lr)*DK + 32 + lq*8);

    bf16x8 ones;
    #pragma unroll
    for (int i = 0; i < 8; i++) ones[i] = (bf16_t)1.0f;

    f32x4 accA[4] = {}, accB[4] = {};
    f32x4 alA = {}, alB = {};

    const int nIter = 32 - qtA;          // 17..32, block-uniform

    ASTAGE(Ks0, Vs0, 0);
    int t = 0;
    while (true) {
        AITER(Ks0, Vs0, Ks1, Vs1, t); t++;
        if (t >= nIter) break;
        AITER(Ks1, Vs1, Ks0, Vs0, t); t++;
        if (t >= nIter) break;
    }

    const int b = bh / NH, h = bh % NH;
    #pragma unroll
    for (int r = 0; r < 4; r++) {
        float rlA = 1.0f / alA[r];
        float rlB = 1.0f / alB[r];
        int qa = qsA + lq*4 + r;
        int qb = qsB + lq*4 + r;
        bf16_t* opA = O + (size_t)(b*SEQ + qa)*DMODEL + h*DK;
        bf16_t* opB = O + (size_t)(b*SEQ + qb)*DMODEL + h*DK;
        #pragma unroll
        for (int c = 0; c < 4; c++) {
            opA[c*16 + lr] = (bf16_t)(accA[c][r] * rlA);
            opB[c*16 + lr] = (bf16_t)(accB[c][r] * rlB);
        }
    }
}

extern "C" void kernel_launch(void* const* d_in, const int* in_sizes, int n_in,
                              void* d_out, int out_size, void* d_ws, size_t ws_size,
                              hipStream_t stream) {
    const float* x    = (const float*)d_in[0];
    const float* wqkv = (const float*)d_in[1];
    const float* wo   = (const float*)d_in[2];
    float* out = (float*)d_out;

    char* ws = (char*)d_ws;
    const size_t SZ_X   = (size_t)NTOK*DMODEL*2;
    const size_t SZ_WQ  = (size_t)3*DMODEL*DMODEL*2;
    const size_t SZ_WO  = (size_t)DMODEL*DMODEL*2;
    const size_t SZ_HD  = (size_t)NB*NH*SEQ*DK*2;
    bf16_t* xb    = (bf16_t*)(ws);
    bf16_t* wqkvb = (bf16_t*)(ws + SZ_X);
    bf16_t* wob   = (bf16_t*)(ws + SZ_X + SZ_WQ);
    bf16_t* Qb    = (bf16_t*)(ws + SZ_X + SZ_WQ + SZ_WO);
    bf16_t* Kb    = (bf16_t*)(ws + SZ_X + SZ_WQ + SZ_WO + SZ_HD);
    bf16_t* VTb   = (bf16_t*)(ws + SZ_X + SZ_WQ + SZ_WO + 2*SZ_HD);
    bf16_t* Ob    = (bf16_t*)(ws + SZ_X + SZ_WQ + SZ_WO + 3*SZ_HD);

    cvt_all<<<(N_X4 + N_WQ4 + N_WO4) / 256, 256, 0, stream>>>(x, wqkv, wo, xb);

    gemm_qkv<<<dim3(NTOK/128, 3*DMODEL/192), 256, 0, stream>>>(xb, wqkvb, Qb, Kb, VTb);
    attn<<<dim3(16, NB*NH), 256, 0, stream>>>(Qb, Kb, VTb, Ob);
    gemm_oproj<<<dim3(NTOK/128, DMODEL/64), 256, 0, stream>>>(Ob, wob, out);
}

// Round 11
// 187.771 us; speedup vs baseline: 1.2621x; 1.0378x over previous
//
#include <hip/hip_runtime.h>
#include <hip/hip_bf16.h>
#include <stdint.h>

#define SEQ 2048
#define NB 4
#define NH 12
#define DMODEL 768
#define DK 64
#define NTOK (NB*SEQ)          // 8192
#define QSCALE 0.18033688011f  // 0.125 * log2(e)

#define N_X4   (NTOK*DMODEL/4)          // 1572864
#define N_WQ4  (3*DMODEL*DMODEL/4)      // 442368
#define N_WO4  (DMODEL*DMODEL/4)        // 147456

typedef __bf16 bf16_t;
typedef __attribute__((ext_vector_type(4))) bf16_t bf16x4;
typedef __attribute__((ext_vector_type(8))) bf16_t bf16x8;
typedef __attribute__((ext_vector_type(4))) float f32x4;

typedef __attribute__((address_space(3))) uint32_t lds_u32_t;
typedef const __attribute__((address_space(1))) uint32_t glb_u32_t;

__device__ inline void load_lds16(const void* g, void* l) {
    __builtin_amdgcn_global_load_lds((glb_u32_t*)g, (lds_u32_t*)l, 16, 0, 0);
}

// ---------------- fp32 -> bf16 convert (x, wqkv, wo fused; dst regions contiguous) ----------------
__global__ void cvt_all(const float* __restrict__ x, const float* __restrict__ wq,
                        const float* __restrict__ wo, bf16_t* __restrict__ dst) {
    int i = blockIdx.x * blockDim.x + threadIdx.x;   // grid sized exactly
    const float* src; int off;
    if (i < N_X4)              { src = x;  off = i; }
    else if (i < N_X4 + N_WQ4) { src = wq; off = i - N_X4; }
    else                       { src = wo; off = i - (N_X4 + N_WQ4); }
    float4 v = ((const float4*)src)[off];
    bf16x4 o;
    o[0] = (bf16_t)v.x; o[1] = (bf16_t)v.y; o[2] = (bf16_t)v.z; o[3] = (bf16_t)v.w;
    ((bf16x4*)dst)[i] = o;
}

// =================== QKV GEMM: 128x192 tile, BK=32, dbuf distinct LDS arrays (R10-proven) ===================
#define QSTAGE(AS, BS, KB) do { \
    _Pragma("unroll") \
    for (int j = 0; j < 5; j++) { \
        int c = tid + j*256; \
        if (c < 512) { \
            int row = c >> 2, cb = (c & 3) * 8; \
            load_lds16(Ap_ + (size_t)(mt*128 + row)*DMODEL + (KB) + cb, AS + c*8); \
        } else { \
            int c2 = c - 512; \
            int row = c2 >> 2, cb = (c2 & 3) * 8; \
            load_lds16(Bp_ + (size_t)(nt*192 + row)*DMODEL + (KB) + cb, BS + c2*8); \
        } \
    } \
} while (0)

#define QCOMPUTE(AS, BS) do { \
    bf16x8 af[4]; \
    _Pragma("unroll") \
    for (int f = 0; f < 4; f++) \
        af[f] = *(const bf16x8*)(AS + (wy*64 + f*16 + lr)*32 + lq*8); \
    _Pragma("unroll") \
    for (int fn = 0; fn < 6; fn++) { \
        bf16x8 bfr = *(const bf16x8*)(BS + (wx*96 + fn*16 + lr)*32 + lq*8); \
        _Pragma("unroll") \
        for (int fm = 0; fm < 4; fm++) \
            acc[fm][fn] = __builtin_amdgcn_mfma_f32_16x16x32_bf16(af[fm], bfr, acc[fm][fn], 0, 0, 0); \
    } \
} while (0)

__global__ __launch_bounds__(256, 3) void gemm_qkv(
    const bf16_t* __restrict__ Ap_, const bf16_t* __restrict__ Bp_,
    bf16_t* __restrict__ Qo, bf16_t* __restrict__ Ko, bf16_t* __restrict__ VTo)
{
    __shared__ bf16_t As0[128*32];
    __shared__ bf16_t Bs0[192*32];
    __shared__ bf16_t As1[128*32];
    __shared__ bf16_t Bs1[192*32];
    const int mt = blockIdx.x, nt = blockIdx.y;
    const int tid = threadIdx.x;
    const int w = tid >> 6, lane = tid & 63;
    const int wx = w & 1, wy = w >> 1;
    const int lr = lane & 15, lq = lane >> 4;

    f32x4 acc[4][6] = {};
    QSTAGE(As0, Bs0, 0);
    for (int kb = 0; kb < DMODEL; kb += 64) {
        __syncthreads();
        QSTAGE(As1, Bs1, kb + 32);
        QCOMPUTE(As0, Bs0);
        __syncthreads();
        if (kb + 64 < DMODEL) QSTAGE(As0, Bs0, kb + 64);
        QCOMPUTE(As1, Bs1);
    }

    const int t = nt >> 2;                      // 768 = 4*192: tile never spans Q/K/V
    const int ob = (nt & 3) * 192 + wx * 96;    // col base within 768
    #pragma unroll
    for (int fm = 0; fm < 4; fm++)
        #pragma unroll
        for (int fn = 0; fn < 6; fn++)
            #pragma unroll
            for (int r = 0; r < 4; r++) {
                int m = mt*128 + wy*64 + fm*16 + lq*4 + r;
                int o = ob + fn*16 + lr;
                int b = m >> 11, s = m & 2047;
                int h = o >> 6, dk = o & 63;
                float v = acc[fm][fn][r];
                if (t == 0)      Qo[(size_t)((b*NH + h)*SEQ + s)*DK + dk] = (bf16_t)(v * QSCALE);
                else if (t == 1) Ko[(size_t)((b*NH + h)*SEQ + s)*DK + dk] = (bf16_t)v;
                else             VTo[(size_t)((b*NH + h)*DK + dk)*SEQ + s] = (bf16_t)v;
            }
}

// ---------------- O projection GEMM: 128x64 tile, grid (64,12)=768 = exactly 3/CU ----------------
#define OSTAGE(AS, BS, KB) do { \
    _Pragma("unroll") \
    for (int j = 0; j < 3; j++) { \
        int c = tid + j*256; \
        if (c < 512) { \
            int row = c >> 2, cb = (c & 3) * 8; \
            load_lds16(Ap_ + (size_t)(mt*128 + row)*DMODEL + (KB) + cb, AS + c*8); \
        } else { \
            int c2 = c - 512; \
            int row = c2 >> 2, cb = (c2 & 3) * 8; \
            load_lds16(Bp_ + (size_t)(nt*64 + row)*DMODEL + (KB) + cb, BS + c2*8); \
        } \
    } \
} while (0)

#define OCOMPUTE(AS, BS) do { \
    bf16x8 af[4], bfr[2]; \
    _Pragma("unroll") \
    for (int f = 0; f < 4; f++) \
        af[f]  = *(const bf16x8*)(AS + (wy*64 + f*16 + lr)*32 + lq*8); \
    _Pragma("unroll") \
    for (int f = 0; f < 2; f++) \
        bfr[f] = *(const bf16x8*)(BS + (wx*32 + f*16 + lr)*32 + lq*8); \
    _Pragma("unroll") \
    for (int fm = 0; fm < 4; fm++) \
        _Pragma("unroll") \
        for (int fn = 0; fn < 2; fn++) \
            acc[fm][fn] = __builtin_amdgcn_mfma_f32_16x16x32_bf16(af[fm], bfr[fn], acc[fm][fn], 0, 0, 0); \
} while (0)

__global__ __launch_bounds__(256, 4) void gemm_oproj(
    const bf16_t* __restrict__ Ap_, const bf16_t* __restrict__ Bp_, float* __restrict__ out)
{
    __shared__ bf16_t As0[128*32];
    __shared__ bf16_t Bs0[64*32];
    __shared__ bf16_t As1[128*32];
    __shared__ bf16_t Bs1[64*32];
    const int mt = blockIdx.x, nt = blockIdx.y;
    const int tid = threadIdx.x;
    const int w = tid >> 6, lane = tid & 63;
    const int wx = w & 1, wy = w >> 1;
    const int lr = lane & 15, lq = lane >> 4;

    f32x4 acc[4][2] = {};
    OSTAGE(As0, Bs0, 0);
    for (int kb = 0; kb < DMODEL; kb += 64) {
        __syncthreads();
        OSTAGE(As1, Bs1, kb + 32);
        OCOMPUTE(As0, Bs0);
        __syncthreads();
        if (kb + 64 < DMODEL) OSTAGE(As0, Bs0, kb + 64);
        OCOMPUTE(As1, Bs1);
    }

    #pragma unroll
    for (int fm = 0; fm < 4; fm++)
        #pragma unroll
        for (int fn = 0; fn < 2; fn++)
            #pragma unroll
            for (int r = 0; r < 4; r++) {
                int m = mt*128 + wy*64 + fm*16 + lq*4 + r;
                int n = nt*64 + wx*32 + fn*16 + lr;
                out[(size_t)m*DMODEL + n] = acc[fm][fn][r];
            }
}

// ---------------- Flash attention (causal) — paired q-tiles + XCD-local grid ----------------
// GRID TRANSPOSED (48,16): bh = blockIdx.x, qt-pair = blockIdx.y. Linear block id
// L = bh + 48*by -> XCD = bh%8 (48 = 0 mod 8): all 16 blocks of a head share one XCD;
// each XCD serves 6 heads; all 768 blocks co-resident (3/CU) -> per-XCD K/V working set
// 6 x 512 KB = 3 MB < 4 MB L2 -> staging DMA becomes L2-hit (~250 cyc), prefetch always
// lands inside the compute window. Everything else identical to the R8/R6-proven version.
#define ASTAGE(KS, VS, KB) do { \
    _Pragma("unroll") \
    for (int j = 0; j < 2; j++) { \
        int rr = w*16 + j*8 + srow; \
        load_lds16(Kp + (size_t)((KB) + rr)*DK + g*8,  &KS[w*1024 + j*512 + lane*8]); \
        load_lds16(Vp + (size_t)rr*SEQ + (KB) + g*8,   &VS[w*1024 + j*512 + lane*8]); \
    } \
} while (0)

#define STRIP(A0, A1, ACC, AL, MASKED) do { \
    f32x4 sc[4]; \
    _Pragma("unroll") \
    for (int ct = 0; ct < 4; ct++) { \
        f32x4 s = {}; \
        s = __builtin_amdgcn_mfma_f32_16x16x32_bf16(A0, bk[ct][0], s, 0, 0, 0); \
        s = __builtin_amdgcn_mfma_f32_16x16x32_bf16(A1, bk[ct][1], s, 0, 0, 0); \
        sc[ct] = s; \
    } \
    _Pragma("unroll") \
    for (int ct = 0; ct < 4; ct++) \
        _Pragma("unroll") \
        for (int r = 0; r < 4; r++) { \
            float p = __builtin_amdgcn_exp2f(sc[ct][r]); \
            if (MASKED) { \
                int kl = ct*16 + lr, ql = w*16 + lq*4 + r; \
                p = (kl <= ql) ? p : 0.0f; \
            } \
            Pw[(ct>>1)*512 + (lq*4 + r + 16*((ct*2 + (lr>>3)) & 3))*8 + ((lr&7)>>1)*2 + (lr&1)] = (bf16_t)p; \
        } \
    { \
        bf16x8 ap0 = *(const bf16x8*)(Pw + lane*8); \
        bf16x8 ap1 = *(const bf16x8*)(Pw + 512 + lane*8); \
        _Pragma("unroll") \
        for (int c = 0; c < 4; c++) { \
            ACC[c] = __builtin_amdgcn_mfma_f32_16x16x32_bf16(ap0, bv[c][0], ACC[c], 0, 0, 0); \
            ACC[c] = __builtin_amdgcn_mfma_f32_16x16x32_bf16(ap1, bv[c][1], ACC[c], 0, 0, 0); \
        } \
        AL = __builtin_amdgcn_mfma_f32_16x16x32_bf16(ap0, ones, AL, 0, 0, 0); \
        AL = __builtin_amdgcn_mfma_f32_16x16x32_bf16(ap1, ones, AL, 0, 0, 0); \
    } \
} while (0)

#define AITER(KSC, VSC, KSN, VSN, T) do { \
    __syncthreads(); \
    if ((T) + 1 < nIter) ASTAGE(KSN, VSN, ((T)+1)*64); \
    bf16x8 bk[4][2], bv[4][2]; \
    const int sw = lr & 7; \
    _Pragma("unroll") \
    for (int ct = 0; ct < 4; ct++) { \
        int row = ct*16 + lr; \
        bk[ct][0] = *(const bf16x8*)(&KSC[row*64 + ((lq    ) ^ sw)*8]); \
        bk[ct][1] = *(const bf16x8*)(&KSC[row*64 + ((lq + 4) ^ sw)*8]); \
        bv[ct][0] = *(const bf16x8*)(&VSC[row*64 + ((lq    ) ^ sw)*8]); \
        bv[ct][1] = *(const bf16x8*)(&VSC[row*64 + ((lq + 4) ^ sw)*8]); \
    } \
    if ((T) <= qtA) { \
        if ((T) == qtA) { STRIP(aqA0, aqA1, accA, alA, true); } \
        else            { STRIP(aqA0, aqA1, accA, alA, false); } \
    } \
    if ((T) == nIter - 1) { STRIP(aqB0, aqB1, accB, alB, true); } \
    else                  { STRIP(aqB0, aqB1, accB, alB, false); } \
} while (0)

__global__ __launch_bounds__(256, 3) void attn(
    const bf16_t* __restrict__ Q, const bf16_t* __restrict__ K,
    const bf16_t* __restrict__ VT, bf16_t* __restrict__ O)
{
    __shared__ bf16_t Ks0[64*64];
    __shared__ bf16_t Vs0[64*64];
    __shared__ bf16_t Ks1[64*64];
    __shared__ bf16_t Vs1[64*64];
    __shared__ bf16_t P[4][1024];

    const int bh  = blockIdx.x;          // 0..47  -> XCD = bh % 8
    const int qtA = blockIdx.y;          // 0..15
    const int qtB = 31 - qtA;            // 16..31
    const int w = threadIdx.x >> 6, lane = threadIdx.x & 63;
    const int lr = lane & 15, lq = lane >> 4;
    const int qsA = qtA*64 + w*16;
    const int qsB = qtB*64 + w*16;
    const int srow = lane >> 3;              // 0..7
    const int g    = (lane & 7) ^ srow;      // XOR-swizzled chunk to fetch

    const bf16_t* Qp = Q  + (size_t)bh*SEQ*DK;
    const bf16_t* Kp = K  + (size_t)bh*SEQ*DK;
    const bf16_t* Vp = VT + (size_t)bh*DK*SEQ;
    bf16_t* Pw = &P[w][0];

    const bf16x8 aqA0 = *(const bf16x8*)(Qp + (size_t)(qsA+lr)*DK + lq*8);
    const bf16x8 aqA1 = *(const bf16x8*)(Qp + (size_t)(qsA+lr)*DK + 32 + lq*8);
    const bf16x8 aqB0 = *(const bf16x8*)(Qp + (size_t)(qsB+lr)*DK + lq*8);
    const bf16x8 aqB1 = *(const bf16x8*)(Qp + (size_t)(qsB+lr)*DK + 32 + lq*8);

    bf16x8 ones;
    #pragma unroll
    for (int i = 0; i < 8; i++) ones[i] = (bf16_t)1.0f;

    f32x4 accA[4] = {}, accB[4] = {};
    f32x4 alA = {}, alB = {};

    const int nIter = 32 - qtA;          // 17..32, block-uniform

    ASTAGE(Ks0, Vs0, 0);
    int t = 0;
    while (true) {
        AITER(Ks0, Vs0, Ks1, Vs1, t); t++;
        if (t >= nIter) break;
        AITER(Ks1, Vs1, Ks0, Vs0, t); t++;
        if (t >= nIter) break;
    }

    const int b = bh / NH, h = bh % NH;
    #pragma unroll
    for (int r = 0; r < 4; r++) {
        float rlA = 1.0f / alA[r];
        float rlB = 1.0f / alB[r];
        int qa = qsA + lq*4 + r;
        int qb = qsB + lq*4 + r;
        bf16_t* opA = O + (size_t)(b*SEQ + qa)*DMODEL + h*DK;
        bf16_t* opB = O + (size_t)(b*SEQ + qb)*DMODEL + h*DK;
        #pragma unroll
        for (int c = 0; c < 4; c++) {
            opA[c*16 + lr] = (bf16_t)(accA[c][r] * rlA);
            opB[c*16 + lr] = (bf16_t)(accB[c][r] * rlB);
        }
    }
}

extern "C" void kernel_launch(void* const* d_in, const int* in_sizes, int n_in,
                              void* d_out, int out_size, void* d_ws, size_t ws_size,
                              hipStream_t stream) {
    const float* x    = (const float*)d_in[0];
    const float* wqkv = (const float*)d_in[1];
    const float* wo   = (const float*)d_in[2];
    float* out = (float*)d_out;

    char* ws = (char*)d_ws;
    const size_t SZ_X   = (size_t)NTOK*DMODEL*2;
    const size_t SZ_WQ  = (size_t)3*DMODEL*DMODEL*2;
    const size_t SZ_WO  = (size_t)DMODEL*DMODEL*2;
    const size_t SZ_HD  = (size_t)NB*NH*SEQ*DK*2;
    bf16_t* xb    = (bf16_t*)(ws);
    bf16_t* wqkvb = (bf16_t*)(ws + SZ_X);
    bf16_t* wob   = (bf16_t*)(ws + SZ_X + SZ_WQ);
    bf16_t* Qb    = (bf16_t*)(ws + SZ_X + SZ_WQ + SZ_WO);
    bf16_t* Kb    = (bf16_t*)(ws + SZ_X + SZ_WQ + SZ_WO + SZ_HD);
    bf16_t* VTb   = (bf16_t*)(ws + SZ_X + SZ_WQ + SZ_WO + 2*SZ_HD);
    bf16_t* Ob    = (bf16_t*)(ws + SZ_X + SZ_WQ + SZ_WO + 3*SZ_HD);

    cvt_all<<<(N_X4 + N_WQ4 + N_WO4) / 256, 256, 0, stream>>>(x, wqkv, wo, xb);

    gemm_qkv<<<dim3(NTOK/128, 3*DMODEL/192), 256, 0, stream>>>(xb, wqkvb, Qb, Kb, VTb);
    attn<<<dim3(NB*NH, 16), 256, 0, stream>>>(Qb, Kb, VTb, Ob);
    gemm_oproj<<<dim3(NTOK/128, DMODEL/64), 256, 0, stream>>>(Ob, wob, out);
}

// Round 12
// 179.942 us; speedup vs baseline: 1.3170x; 1.0435x over previous
//
#include <hip/hip_runtime.h>
#include <hip/hip_bf16.h>
#include <stdint.h>

#define SEQ 2048
#define NB 4
#define NH 12
#define DMODEL 768
#define DK 64
#define NTOK (NB*SEQ)          // 8192
#define QSCALE 0.18033688011f  // 0.125 * log2(e)

#define N_X4   (NTOK*DMODEL/4)          // 1572864
#define N_WQ4  (3*DMODEL*DMODEL/4)      // 442368
#define N_WO4  (DMODEL*DMODEL/4)        // 147456

typedef __bf16 bf16_t;
typedef __attribute__((ext_vector_type(4))) bf16_t bf16x4;
typedef __attribute__((ext_vector_type(8))) bf16_t bf16x8;
typedef __attribute__((ext_vector_type(4))) float f32x4;

typedef __attribute__((address_space(3))) uint32_t lds_u32_t;
typedef const __attribute__((address_space(1))) uint32_t glb_u32_t;

__device__ inline void load_lds16(const void* g, void* l) {
    __builtin_amdgcn_global_load_lds((glb_u32_t*)g, (lds_u32_t*)l, 16, 0, 0);
}

// ---------------- fp32 -> bf16 convert (x, wqkv, wo fused; dst regions contiguous) ----------------
__global__ void cvt_all(const float* __restrict__ x, const float* __restrict__ wq,
                        const float* __restrict__ wo, bf16_t* __restrict__ dst) {
    int i = blockIdx.x * blockDim.x + threadIdx.x;   // grid sized exactly
    const float* src; int off;
    if (i < N_X4)              { src = x;  off = i; }
    else if (i < N_X4 + N_WQ4) { src = wq; off = i - N_X4; }
    else                       { src = wo; off = i - (N_X4 + N_WQ4); }
    float4 v = ((const float4*)src)[off];
    bf16x4 o;
    o[0] = (bf16_t)v.x; o[1] = (bf16_t)v.y; o[2] = (bf16_t)v.z; o[3] = (bf16_t)v.w;
    ((bf16x4*)dst)[i] = o;
}

// =================== QKV GEMM: 128x192 tile, BK=32, dbuf distinct LDS arrays (R10-proven) ===================
#define QSTAGE(AS, BS, KB) do { \
    _Pragma("unroll") \
    for (int j = 0; j < 5; j++) { \
        int c = tid + j*256; \
        if (c < 512) { \
            int row = c >> 2, cb = (c & 3) * 8; \
            load_lds16(Ap_ + (size_t)(mt*128 + row)*DMODEL + (KB) + cb, AS + c*8); \
        } else { \
            int c2 = c - 512; \
            int row = c2 >> 2, cb = (c2 & 3) * 8; \
            load_lds16(Bp_ + (size_t)(nt*192 + row)*DMODEL + (KB) + cb, BS + c2*8); \
        } \
    } \
} while (0)

#define QCOMPUTE(AS, BS) do { \
    bf16x8 af[4]; \
    _Pragma("unroll") \
    for (int f = 0; f < 4; f++) \
        af[f] = *(const bf16x8*)(AS + (wy*64 + f*16 + lr)*32 + lq*8); \
    _Pragma("unroll") \
    for (int fn = 0; fn < 6; fn++) { \
        bf16x8 bfr = *(const bf16x8*)(BS + (wx*96 + fn*16 + lr)*32 + lq*8); \
        _Pragma("unroll") \
        for (int fm = 0; fm < 4; fm++) \
            acc[fm][fn] = __builtin_amdgcn_mfma_f32_16x16x32_bf16(af[fm], bfr, acc[fm][fn], 0, 0, 0); \
    } \
} while (0)

__global__ __launch_bounds__(256, 3) void gemm_qkv(
    const bf16_t* __restrict__ Ap_, const bf16_t* __restrict__ Bp_,
    bf16_t* __restrict__ Qo, bf16_t* __restrict__ Ko, bf16_t* __restrict__ VTo)
{
    __shared__ bf16_t As0[128*32];
    __shared__ bf16_t Bs0[192*32];
    __shared__ bf16_t As1[128*32];
    __shared__ bf16_t Bs1[192*32];
    const int mt = blockIdx.x, nt = blockIdx.y;
    const int tid = threadIdx.x;
    const int w = tid >> 6, lane = tid & 63;
    const int wx = w & 1, wy = w >> 1;
    const int lr = lane & 15, lq = lane >> 4;

    f32x4 acc[4][6] = {};
    QSTAGE(As0, Bs0, 0);
    for (int kb = 0; kb < DMODEL; kb += 64) {
        __syncthreads();
        QSTAGE(As1, Bs1, kb + 32);
        QCOMPUTE(As0, Bs0);
        __syncthreads();
        if (kb + 64 < DMODEL) QSTAGE(As0, Bs0, kb + 64);
        QCOMPUTE(As1, Bs1);
    }

    const int t = nt >> 2;                      // 768 = 4*192: tile never spans Q/K/V
    const int ob = (nt & 3) * 192 + wx * 96;    // col base within 768
    if (t == 2) {
        // V: r=0..3 are s-contiguous -> packed b64 stores
        #pragma unroll
        for (int fm = 0; fm < 4; fm++)
            #pragma unroll
            for (int fn = 0; fn < 6; fn++) {
                int m0 = mt*128 + wy*64 + fm*16 + lq*4;
                int o = ob + fn*16 + lr;
                int b = m0 >> 11, s0 = m0 & 2047;
                int h = o >> 6, dk = o & 63;
                bf16x4 v4;
                #pragma unroll
                for (int r = 0; r < 4; r++) v4[r] = (bf16_t)acc[fm][fn][r];
                *(bf16x4*)(VTo + (size_t)((b*NH + h)*DK + dk)*SEQ + s0) = v4;
            }
    } else {
        #pragma unroll
        for (int fm = 0; fm < 4; fm++)
            #pragma unroll
            for (int fn = 0; fn < 6; fn++)
                #pragma unroll
                for (int r = 0; r < 4; r++) {
                    int m = mt*128 + wy*64 + fm*16 + lq*4 + r;
                    int o = ob + fn*16 + lr;
                    int b = m >> 11, s = m & 2047;
                    int h = o >> 6, dk = o & 63;
                    float v = acc[fm][fn][r];
                    if (t == 0) Qo[(size_t)((b*NH + h)*SEQ + s)*DK + dk] = (bf16_t)(v * QSCALE);
                    else        Ko[(size_t)((b*NH + h)*SEQ + s)*DK + dk] = (bf16_t)v;
                }
    }
}

// ---------------- O projection GEMM: 128x64 tile, grid (64,12)=768 = exactly 3/CU ----------------
#define OSTAGE(AS, BS, KB) do { \
    _Pragma("unroll") \
    for (int j = 0; j < 3; j++) { \
        int c = tid + j*256; \
        if (c < 512) { \
            int row = c >> 2, cb = (c & 3) * 8; \
            load_lds16(Ap_ + (size_t)(mt*128 + row)*DMODEL + (KB) + cb, AS + c*8); \
        } else { \
            int c2 = c - 512; \
            int row = c2 >> 2, cb = (c2 & 3) * 8; \
            load_lds16(Bp_ + (size_t)(nt*64 + row)*DMODEL + (KB) + cb, BS + c2*8); \
        } \
    } \
} while (0)

#define OCOMPUTE(AS, BS) do { \
    bf16x8 af[4], bfr[2]; \
    _Pragma("unroll") \
    for (int f = 0; f < 4; f++) \
        af[f]  = *(const bf16x8*)(AS + (wy*64 + f*16 + lr)*32 + lq*8); \
    _Pragma("unroll") \
    for (int f = 0; f < 2; f++) \
        bfr[f] = *(const bf16x8*)(BS + (wx*32 + f*16 + lr)*32 + lq*8); \
    _Pragma("unroll") \
    for (int fm = 0; fm < 4; fm++) \
        _Pragma("unroll") \
        for (int fn = 0; fn < 2; fn++) \
            acc[fm][fn] = __builtin_amdgcn_mfma_f32_16x16x32_bf16(af[fm], bfr[fn], acc[fm][fn], 0, 0, 0); \
} while (0)

__global__ __launch_bounds__(256, 4) void gemm_oproj(
    const bf16_t* __restrict__ Ap_, const bf16_t* __restrict__ Bp_, float* __restrict__ out)
{
    __shared__ bf16_t As0[128*32];
    __shared__ bf16_t Bs0[64*32];
    __shared__ bf16_t As1[128*32];
    __shared__ bf16_t Bs1[64*32];
    const int mt = blockIdx.x, nt = blockIdx.y;
    const int tid = threadIdx.x;
    const int w = tid >> 6, lane = tid & 63;
    const int wx = w & 1, wy = w >> 1;
    const int lr = lane & 15, lq = lane >> 4;

    f32x4 acc[4][2] = {};
    OSTAGE(As0, Bs0, 0);
    for (int kb = 0; kb < DMODEL; kb += 64) {
        __syncthreads();
        OSTAGE(As1, Bs1, kb + 32);
        OCOMPUTE(As0, Bs0);
        __syncthreads();
        if (kb + 64 < DMODEL) OSTAGE(As0, Bs0, kb + 64);
        OCOMPUTE(As1, Bs1);
    }

    #pragma unroll
    for (int fm = 0; fm < 4; fm++)
        #pragma unroll
        for (int fn = 0; fn < 2; fn++)
            #pragma unroll
            for (int r = 0; r < 4; r++) {
                int m = mt*128 + wy*64 + fm*16 + lq*4 + r;
                int n = nt*64 + wx*32 + fn*16 + lr;
                out[(size_t)m*DMODEL + n] = acc[fm][fn][r];
            }
}

// ---------------- Flash attention (causal) — paired q-tiles, XCD-local grid, permuted-K P-pack ----------------
// K rows staged permuted (sigma(rr) = (rr&15)*4 + (rr>>4)) so the score at (ct,lr) is the key
// kb + lr*4+ct -> each lane's 4 ct-values are CONTIGUOUS u16 in the consumer A-layout:
// P-write = 4x ds_write_b64 (was 16x ds_write_b16) + paired cvts. 16B-block XOR swizzle
// T(idx)=idx^(((idx>>7)&3)<<4) applied by writer AND reader: write banking 16-way -> 4-way.
// V staging/columns stay natural order (PV pairs P col k with V col k). Mask: kl = lr*4+ct.
#define ASTAGE(KS, VS, KB) do { \
    _Pragma("unroll") \
    for (int j = 0; j < 2; j++) { \
        int rr = w*16 + j*8 + srow; \
        int kperm = (j*8 + srow)*4 + w;  /* sigma(rr) */ \
        load_lds16(Kp + (size_t)((KB) + kperm)*DK + g*8,  &KS[w*1024 + j*512 + lane*8]); \
        load_lds16(Vp + (size_t)rr*SEQ + (KB) + g*8,   &VS[w*1024 + j*512 + lane*8]); \
    } \
} while (0)

#define STRIP(A0, A1, ACC, AL, MASKED) do { \
    f32x4 sc[4]; \
    _Pragma("unroll") \
    for (int ct = 0; ct < 4; ct++) { \
        f32x4 s = {}; \
        s = __builtin_amdgcn_mfma_f32_16x16x32_bf16(A0, bk[ct][0], s, 0, 0, 0); \
        s = __builtin_amdgcn_mfma_f32_16x16x32_bf16(A1, bk[ct][1], s, 0, 0, 0); \
        sc[ct] = s; \
    } \
    _Pragma("unroll") \
    for (int r = 0; r < 4; r++) { \
        bf16x4 p4; \
        _Pragma("unroll") \
        for (int ct = 0; ct < 4; ct++) { \
            float p = __builtin_amdgcn_exp2f(sc[ct][r]); \
            if (MASKED) { \
                int kl = lr*4 + ct, ql = w*16 + lq*4 + r; \
                p = (kl <= ql) ? p : 0.0f; \
            } \
            p4[ct] = (bf16_t)p; \
        } \
        *(bf16x4*)(Pw + ((((lr>>3)*512 + (lq*4 + r + 16*((lr>>1)&3))*8 + (lr&1)*4)) ^ (((lr>>1)&3) << 4))) = p4; \
    } \
    { \
        bf16x8 ap0 = *(const bf16x8*)(Pw + ((lane ^ (lq<<1))*8)); \
        bf16x8 ap1 = *(const bf16x8*)(Pw + 512 + ((lane ^ (lq<<1))*8)); \
        _Pragma("unroll") \
        for (int c = 0; c < 4; c++) { \
            ACC[c] = __builtin_amdgcn_mfma_f32_16x16x32_bf16(ap0, bv[c][0], ACC[c], 0, 0, 0); \
            ACC[c] = __builtin_amdgcn_mfma_f32_16x16x32_bf16(ap1, bv[c][1], ACC[c], 0, 0, 0); \
        } \
        AL = __builtin_amdgcn_mfma_f32_16x16x32_bf16(ap0, ones, AL, 0, 0, 0); \
        AL = __builtin_amdgcn_mfma_f32_16x16x32_bf16(ap1, ones, AL, 0, 0, 0); \
    } \
} while (0)

#define AITER(KSC, VSC, KSN, VSN, T) do { \
    __syncthreads(); \
    if ((T) + 1 < nIter) ASTAGE(KSN, VSN, ((T)+1)*64); \
    bf16x8 bk[4][2], bv[4][2]; \
    const int sw = lr & 7; \
    _Pragma("unroll") \
    for (int ct = 0; ct < 4; ct++) { \
        int row = ct*16 + lr; \
        bk[ct][0] = *(const bf16x8*)(&KSC[row*64 + ((lq    ) ^ sw)*8]); \
        bk[ct][1] = *(const bf16x8*)(&KSC[row*64 + ((lq + 4) ^ sw)*8]); \
        bv[ct][0] = *(const bf16x8*)(&VSC[row*64 + ((lq    ) ^ sw)*8]); \
        bv[ct][1] = *(const bf16x8*)(&VSC[row*64 + ((lq + 4) ^ sw)*8]); \
    } \
    if ((T) <= qtA) { \
        if ((T) == qtA) { STRIP(aqA0, aqA1, accA, alA, true); } \
        else            { STRIP(aqA0, aqA1, accA, alA, false); } \
    } \
    if ((T) == nIter - 1) { STRIP(aqB0, aqB1, accB, alB, true); } \
    else                  { STRIP(aqB0, aqB1, accB, alB, false); } \
} while (0)

__global__ __launch_bounds__(256, 3) void attn(
    const bf16_t* __restrict__ Q, const bf16_t* __restrict__ K,
    const bf16_t* __restrict__ VT, bf16_t* __restrict__ O)
{
    __shared__ bf16_t Ks0[64*64];
    __shared__ bf16_t Vs0[64*64];
    __shared__ bf16_t Ks1[64*64];
    __shared__ bf16_t Vs1[64*64];
    __shared__ bf16_t P[4][1024];

    const int bh  = blockIdx.x;          // 0..47  -> XCD = bh % 8
    const int qtA = blockIdx.y;          // 0..15
    const int qtB = 31 - qtA;            // 16..31
    const int w = threadIdx.x >> 6, lane = threadIdx.x & 63;
    const int lr = lane & 15, lq = lane >> 4;
    const int qsA = qtA*64 + w*16;
    const int qsB = qtB*64 + w*16;
    const int srow = lane >> 3;              // 0..7
    const int g    = (lane & 7) ^ srow;      // XOR-swizzled chunk to fetch

    const bf16_t* Qp = Q  + (size_t)bh*SEQ*DK;
    const bf16_t* Kp = K  + (size_t)bh*SEQ*DK;
    const bf16_t* Vp = VT + (size_t)bh*DK*SEQ;
    bf16_t* Pw = &P[w][0];

    const bf16x8 aqA0 = *(const bf16x8*)(Qp + (size_t)(qsA+lr)*DK + lq*8);
    const bf16x8 aqA1 = *(const bf16x8*)(Qp + (size_t)(qsA+lr)*DK + 32 + lq*8);
    const bf16x8 aqB0 = *(const bf16x8*)(Qp + (size_t)(qsB+lr)*DK + lq*8);
    const bf16x8 aqB1 = *(const bf16x8*)(Qp + (size_t)(qsB+lr)*DK + 32 + lq*8);

    bf16x8 ones;
    #pragma unroll
    for (int i = 0; i < 8; i++) ones[i] = (bf16_t)1.0f;

    f32x4 accA[4] = {}, accB[4] = {};
    f32x4 alA = {}, alB = {};

    const int nIter = 32 - qtA;          // 17..32, block-uniform

    ASTAGE(Ks0, Vs0, 0);
    int t = 0;
    while (true) {
        AITER(Ks0, Vs0, Ks1, Vs1, t); t++;
        if (t >= nIter) break;
        AITER(Ks1, Vs1, Ks0, Vs0, t); t++;
        if (t >= nIter) break;
    }

    const int b = bh / NH, h = bh % NH;
    #pragma unroll
    for (int r = 0; r < 4; r++) {
        float rlA = 1.0f / alA[r];
        float rlB = 1.0f / alB[r];
        int qa = qsA + lq*4 + r;
        int qb = qsB + lq*4 + r;
        bf16_t* opA = O + (size_t)(b*SEQ + qa)*DMODEL + h*DK;
        bf16_t* opB = O + (size_t)(b*SEQ + qb)*DMODEL + h*DK;
        #pragma unroll
        for (int c = 0; c < 4; c++) {
            opA[c*16 + lr] = (bf16_t)(accA[c][r] * rlA);
            opB[c*16 + lr] = (bf16_t)(accB[c][r] * rlB);
        }
    }
}

extern "C" void kernel_launch(void* const* d_in, const int* in_sizes, int n_in,
                              void* d_out, int out_size, void* d_ws, size_t ws_size,
                              hipStream_t stream) {
    const float* x    = (const float*)d_in[0];
    const float* wqkv = (const float*)d_in[1];
    const float* wo   = (const float*)d_in[2];
    float* out = (float*)d_out;

    char* ws = (char*)d_ws;
    const size_t SZ_X   = (size_t)NTOK*DMODEL*2;
    const size_t SZ_WQ  = (size_t)3*DMODEL*DMODEL*2;
    const size_t SZ_WO  = (size_t)DMODEL*DMODEL*2;
    const size_t SZ_HD  = (size_t)NB*NH*SEQ*DK*2;
    bf16_t* xb    = (bf16_t*)(ws);
    bf16_t* wqkvb = (bf16_t*)(ws + SZ_X);
    bf16_t* wob   = (bf16_t*)(ws + SZ_X + SZ_WQ);
    bf16_t* Qb    = (bf16_t*)(ws + SZ_X + SZ_WQ + SZ_WO);
    bf16_t* Kb    = (bf16_t*)(ws + SZ_X + SZ_WQ + SZ_WO + SZ_HD);
    bf16_t* VTb   = (bf16_t*)(ws + SZ_X + SZ_WQ + SZ_WO + 2*SZ_HD);
    bf16_t* Ob    = (bf16_t*)(ws + SZ_X + SZ_WQ + SZ_WO + 3*SZ_HD);

    cvt_all<<<(N_X4 + N_WQ4 + N_WO4) / 256, 256, 0, stream>>>(x, wqkv, wo, xb);

    gemm_qkv<<<dim3(NTOK/128, 3*DMODEL/192), 256, 0, stream>>>(xb, wqkvb, Qb, Kb, VTb);
    attn<<<dim3(NB*NH, 16), 256, 0, stream>>>(Qb, Kb, VTb, Ob);
    gemm_oproj<<<dim3(NTOK/128, DMODEL/64), 256, 0, stream>>>(Ob, wob, out);
}